// Round 6
// baseline (2659.309 us; speedup 1.0000x reference)
//
#include <hip/hip_runtime.h>
#include <stdint.h>

// L=512, B=32, D=H=256
// Workspace layout (floats):
//   Eq  [16384*256] @ 0         (exp2(C2*xq))
//   Ev  [16384*256] @ 4194304   (exp2(C2*xv))
//   S   [32*512*512] @ 8388608  (scores, then softmax in place)
//   C   [16384*256] @ 0         (context, reuses Eq region - dead after score_k)
//   Gi2 [f16, 16384*768] @ float-offset 4194304 (reuses Ev+S - dead after ctx_k)

#define C2    2.8853900817779268f   // 2*log2(e)
#define LOG2E 1.4426950408889634f

typedef __fp16 f16x2 __attribute__((ext_vector_type(2)));
typedef __fp16 f16x4_t __attribute__((ext_vector_type(4)));
typedef __fp16 f16x8 __attribute__((ext_vector_type(8)));
typedef float f32x4 __attribute__((ext_vector_type(4)));

static __device__ __forceinline__ float rcp_f(float x)  { return __builtin_amdgcn_rcpf(x); }
static __device__ __forceinline__ float exp2_f(float x) { return __builtin_amdgcn_exp2f(x); }

// ---------------------------------------------------------------------------
// out[m][n] = epilogue( sum_d A[m][d] * W[n][d] ),  K = 256 fixed
// expmode=1: out = exp2(C2*acc); expmode=0: out = acc + bias[n]
// ---------------------------------------------------------------------------
__global__ __launch_bounds__(256) void gemm_nt(
    const float* __restrict__ A, const float* __restrict__ W,
    const float* __restrict__ bias, float* __restrict__ out,
    int N, int expmode)
{
  __shared__ __align__(16) float As[32][68];
  __shared__ __align__(16) float Ws[32][68];
  const int t = threadIdx.x;
  const int tx = t & 15, ty = t >> 4;
  const int n0 = blockIdx.x * 64, m0 = blockIdx.y * 64;
  float acc[4][4] = {};

  for (int k0 = 0; k0 < 256; k0 += 32) {
#pragma unroll
    for (int s = 0; s < 2; ++s) {
      int f = t + s * 256;
      int row = f >> 3, kq = f & 7;
      float4 a = *(const float4*)&A[(size_t)(m0 + row) * 256 + k0 + kq * 4];
      float4 w = *(const float4*)&W[(size_t)(n0 + row) * 256 + k0 + kq * 4];
      As[kq * 4 + 0][row] = a.x; As[kq * 4 + 1][row] = a.y;
      As[kq * 4 + 2][row] = a.z; As[kq * 4 + 3][row] = a.w;
      Ws[kq * 4 + 0][row] = w.x; Ws[kq * 4 + 1][row] = w.y;
      Ws[kq * 4 + 2][row] = w.z; Ws[kq * 4 + 3][row] = w.w;
    }
    __syncthreads();
#pragma unroll
    for (int kk = 0; kk < 32; ++kk) {
      float4 a4 = *(const float4*)&As[kk][ty * 4];
      float4 b4 = *(const float4*)&Ws[kk][tx * 4];
      float av[4] = {a4.x, a4.y, a4.z, a4.w};
      float bv[4] = {b4.x, b4.y, b4.z, b4.w};
#pragma unroll
      for (int r = 0; r < 4; ++r)
#pragma unroll
        for (int c = 0; c < 4; ++c)
          acc[r][c] = fmaf(av[r], bv[c], acc[r][c]);
    }
    __syncthreads();
  }

#pragma unroll
  for (int r = 0; r < 4; ++r) {
    float4 o;
    if (expmode) {
      o.x = exp2_f(C2 * acc[r][0]); o.y = exp2_f(C2 * acc[r][1]);
      o.z = exp2_f(C2 * acc[r][2]); o.w = exp2_f(C2 * acc[r][3]);
    } else {
      float4 bb = *(const float4*)&bias[n0 + tx * 4];
      o.x = acc[r][0] + bb.x; o.y = acc[r][1] + bb.y;
      o.z = acc[r][2] + bb.z; o.w = acc[r][3] + bb.w;
    }
    *(float4*)&out[(size_t)(m0 + ty * 4 + r) * N + n0 + tx * 4] = o;
  }
}

// ---------------------------------------------------------------------------
// Gi gemm: G = C @ Wih^T + (bih + bhh folded for gates r,z; bih only for n).
// Output packed f16 in transposed layout Gi2[i][g][j][b]  (b innermost, 32).
// grid: (12, 256), block 256
// ---------------------------------------------------------------------------
__global__ __launch_bounds__(256) void gemm_gi(
    const float* __restrict__ A, const float* __restrict__ W,
    const float* __restrict__ bih, const float* __restrict__ bhh,
    __fp16* __restrict__ G)
{
  __shared__ __align__(16) float As[32][68];
  __shared__ __align__(16) float Ws[32][68];
  const int t = threadIdx.x;
  const int tx = t & 15, ty = t >> 4;
  const int n0 = blockIdx.x * 64, m0 = blockIdx.y * 64;
  float acc[4][4] = {};

  for (int k0 = 0; k0 < 256; k0 += 32) {
#pragma unroll
    for (int s = 0; s < 2; ++s) {
      int f = t + s * 256;
      int row = f >> 3, kq = f & 7;
      float4 a = *(const float4*)&A[(size_t)(m0 + row) * 256 + k0 + kq * 4];
      float4 w = *(const float4*)&W[(size_t)(n0 + row) * 256 + k0 + kq * 4];
      As[kq * 4 + 0][row] = a.x; As[kq * 4 + 1][row] = a.y;
      As[kq * 4 + 2][row] = a.z; As[kq * 4 + 3][row] = a.w;
      Ws[kq * 4 + 0][row] = w.x; Ws[kq * 4 + 1][row] = w.y;
      Ws[kq * 4 + 2][row] = w.z; Ws[kq * 4 + 3][row] = w.w;
    }
    __syncthreads();
#pragma unroll
    for (int kk = 0; kk < 32; ++kk) {
      float4 a4 = *(const float4*)&As[kk][ty * 4];
      float4 b4 = *(const float4*)&Ws[kk][tx * 4];
      float av[4] = {a4.x, a4.y, a4.z, a4.w};
      float bv[4] = {b4.x, b4.y, b4.z, b4.w};
#pragma unroll
      for (int r = 0; r < 4; ++r)
#pragma unroll
        for (int c = 0; c < 4; ++c)
          acc[r][c] = fmaf(av[r], bv[c], acc[r][c]);
    }
    __syncthreads();
  }

  // bias (fold bhh for gates r,z; gate n keeps bhh separate in gru_k)
  float bias[4];
#pragma unroll
  for (int c = 0; c < 4; ++c) {
    int n = n0 + tx * 4 + c;
    bias[c] = bih[n] + (n < 512 ? bhh[n] : 0.f);
  }
#pragma unroll
  for (int r = 0; r < 4; ++r) {
    int m = m0 + ty * 4 + r;
    int i = m >> 5, b = m & 31;
#pragma unroll
    for (int c = 0; c < 4; ++c) {
      int n = n0 + tx * 4 + c;
      int g = n >> 8, j = n & 255;
      G[(((size_t)i * 3 + g) * 256 + j) * 32 + b] = (__fp16)(acc[r][c] + bias[c]);
    }
  }
}

// ---------------------------------------------------------------------------
// S[b][i][l] = -2 * sum_h Vvec[b][h] * rcp(1 + Eq[i][b][h]*Ev[l][b][h])
// ---------------------------------------------------------------------------
__global__ __launch_bounds__(256) void score_k(
    const float* __restrict__ Eq, const float* __restrict__ Ev,
    const float* __restrict__ Vvec, float* __restrict__ S)
{
  __shared__ __align__(16) float Eqs[64][68];
  __shared__ __align__(16) float Evs[32][68];
  __shared__ __align__(16) float Vs[256];
  const int t = threadIdx.x;
  const int tx = t & 15, ty = t >> 4;
  const int l0 = blockIdx.x * 32;
  const int i0 = blockIdx.y * 64;
  const int b  = blockIdx.z;

  Vs[t] = -2.0f * Vvec[b * 256 + t];
  float acc[4][2] = {};

  for (int st = 0; st < 4; ++st) {
    const int h0 = st * 64;
#pragma unroll
    for (int s = 0; s < 4; ++s) {
      int f = t + s * 256;
      int row = f >> 4, cq = f & 15;
      *(float4*)&Eqs[row][cq * 4] =
          *(const float4*)&Eq[((size_t)(i0 + row) * 32 + b) * 256 + h0 + cq * 4];
    }
#pragma unroll
    for (int s = 0; s < 2; ++s) {
      int f = t + s * 256;
      int row = f >> 4, cq = f & 15;
      *(float4*)&Evs[row][cq * 4] =
          *(const float4*)&Ev[((size_t)(l0 + row) * 32 + b) * 256 + h0 + cq * 4];
    }
    __syncthreads();
#pragma unroll 4
    for (int k4 = 0; k4 < 16; ++k4) {
      float4 vh = *(const float4*)&Vs[h0 + k4 * 4];
      float4 e0 = *(const float4*)&Evs[tx][k4 * 4];
      float4 e1 = *(const float4*)&Evs[tx + 16][k4 * 4];
#pragma unroll
      for (int r = 0; r < 4; ++r) {
        float4 eq = *(const float4*)&Eqs[ty * 4 + r][k4 * 4];
        acc[r][0] += vh.x * rcp_f(fmaf(eq.x, e0.x, 1.0f));
        acc[r][0] += vh.y * rcp_f(fmaf(eq.y, e0.y, 1.0f));
        acc[r][0] += vh.z * rcp_f(fmaf(eq.z, e0.z, 1.0f));
        acc[r][0] += vh.w * rcp_f(fmaf(eq.w, e0.w, 1.0f));
        acc[r][1] += vh.x * rcp_f(fmaf(eq.x, e1.x, 1.0f));
        acc[r][1] += vh.y * rcp_f(fmaf(eq.y, e1.y, 1.0f));
        acc[r][1] += vh.z * rcp_f(fmaf(eq.z, e1.z, 1.0f));
        acc[r][1] += vh.w * rcp_f(fmaf(eq.w, e1.w, 1.0f));
      }
    }
    __syncthreads();
  }

#pragma unroll
  for (int r = 0; r < 4; ++r) {
    float* ps = &S[((size_t)b * 512 + i0 + ty * 4 + r) * 512 + l0];
    ps[tx]      = acc[r][0];
    ps[tx + 16] = acc[r][1];
  }
}

// ---------------------------------------------------------------------------
// In-place softmax over last dim (512) of S viewed as [16384][512].
// ---------------------------------------------------------------------------
__global__ __launch_bounds__(64) void softmax_k(float* __restrict__ S)
{
  const int t = threadIdx.x;
  float* row = &S[(size_t)blockIdx.x * 512];
  float x[8];
  float m = -1e30f;
#pragma unroll
  for (int u = 0; u < 8; ++u) { x[u] = row[t + u * 64]; m = fmaxf(m, x[u]); }
#pragma unroll
  for (int o = 32; o; o >>= 1) m = fmaxf(m, __shfl_xor(m, o, 64));
  float sum = 0.f;
#pragma unroll
  for (int u = 0; u < 8; ++u) { x[u] = exp2_f(LOG2E * (x[u] - m)); sum += x[u]; }
#pragma unroll
  for (int o = 32; o; o >>= 1) sum += __shfl_xor(sum, o, 64);
  float inv = rcp_f(sum);
#pragma unroll
  for (int u = 0; u < 8; ++u) row[t + u * 64] = x[u] * inv;
}

// ---------------------------------------------------------------------------
// C[i][b][d] = sum_l A[b][i][l] * v[l][b][d]
// ---------------------------------------------------------------------------
__global__ __launch_bounds__(256) void ctx_k(
    const float* __restrict__ Aw, const float* __restrict__ v,
    float* __restrict__ C)
{
  __shared__ __align__(16) float As[32][68];
  __shared__ __align__(16) float Vs[32][68];
  const int t = threadIdx.x, tx = t & 15, ty = t >> 4;
  const int d0 = blockIdx.x * 64, i0 = blockIdx.y * 64, b = blockIdx.z;
  float acc[4][4] = {};

  for (int l0 = 0; l0 < 512; l0 += 32) {
#pragma unroll
    for (int s = 0; s < 2; ++s) {
      int f = t + s * 256;
      int row = f >> 3, lq = f & 7;
      float4 a = *(const float4*)&Aw[((size_t)b * 512 + i0 + row) * 512 + l0 + lq * 4];
      As[lq * 4 + 0][row] = a.x; As[lq * 4 + 1][row] = a.y;
      As[lq * 4 + 2][row] = a.z; As[lq * 4 + 3][row] = a.w;
    }
#pragma unroll
    for (int s = 0; s < 2; ++s) {
      int f = t + s * 256;
      int row = f >> 4, dq = f & 15;
      *(float4*)&Vs[row][dq * 4] =
          *(const float4*)&v[((size_t)(l0 + row) * 32 + b) * 256 + d0 + dq * 4];
    }
    __syncthreads();
#pragma unroll
    for (int kk = 0; kk < 32; ++kk) {
      float4 a4 = *(const float4*)&As[kk][ty * 4];
      float4 b4 = *(const float4*)&Vs[kk][tx * 4];
      float av[4] = {a4.x, a4.y, a4.z, a4.w};
      float bv[4] = {b4.x, b4.y, b4.z, b4.w};
#pragma unroll
      for (int r = 0; r < 4; ++r)
#pragma unroll
        for (int c = 0; c < 4; ++c)
          acc[r][c] = fmaf(av[r], bv[c], acc[r][c]);
    }
    __syncthreads();
  }

#pragma unroll
  for (int r = 0; r < 4; ++r) {
    float4 o = {acc[r][0], acc[r][1], acc[r][2], acc[r][3]};
    *(float4*)&C[((size_t)(i0 + ty * 4 + r) * 32 + b) * 256 + d0 + tx * 4] = o;
  }
}

// ---------------------------------------------------------------------------
// MFMA GRU. 2 blocks x 256 threads (4 waves, 1 wave/SIMD -> 512-reg budget).
// Block handles 16 batches (M=16). Per step: Gh = h @ Whh^T as MFMA
// 16x16x32_f16: 1 m-tile x 48 n-tiles x 8 k-steps. Wave owns 4 gate-TRIPLETS
// (j-tiles {j, j+256, j+512}) so r/z/n for each (b,j) land in the same lane
// and acc reg -> in-lane epilogue, no LDS gate-combine. Weights: 384 dwords
// of f16 frags/thread -> arch+AGPR (MFMA reads AGPRs directly, unlike v_dot2
// -- the R2-R5 pathology doesn't apply). h round-trips through an 8KB
// quad-major LDS buffer matching the A-fragment layout exactly
// (A[m=lane&15][k=quad*8+j]); double-buffered, one barrier/step.
// Gi prefetched per step as f16 b64 loads (transposed [i][g][j][b] layout).
// ---------------------------------------------------------------------------
__global__ __launch_bounds__(256, 1) void gru_k(
    const __fp16* __restrict__ Gi2, const float* __restrict__ Whh,
    const float* __restrict__ bhh, const float* __restrict__ h0,
    float* __restrict__ out)
{
  __shared__ __align__(16) __fp16 hA[2][4096];
  const int t = threadIdx.x, wave = t >> 6, lane = t & 63;
  const int quad = lane >> 4, col = lane & 15;
  const int b0 = blockIdx.x * 16;
  const int jw = wave * 64;

  // B fragments: Bf[p][g][kk], lane holds B[k=kk*32+quad*8+jj][n=col] =
  // Whh[g*256 + jw + p*16 + col][kk*32 + quad*8 + jj], jj=0..7
  f16x8 Bf[4][3][8];
#pragma unroll
  for (int p = 0; p < 4; ++p)
#pragma unroll
    for (int g = 0; g < 3; ++g) {
      const float* wrow = &Whh[(size_t)(g * 256 + jw + p * 16 + col) * 256];
#pragma unroll
      for (int kk = 0; kk < 8; ++kk) {
        const float4* wp = (const float4*)&wrow[kk * 32 + quad * 8];
        float4 w0 = wp[0], w1 = wp[1];
        f16x8 f;
        f[0] = (__fp16)w0.x; f[1] = (__fp16)w0.y;
        f[2] = (__fp16)w0.z; f[3] = (__fp16)w0.w;
        f[4] = (__fp16)w1.x; f[5] = (__fp16)w1.y;
        f[6] = (__fp16)w1.z; f[7] = (__fp16)w1.w;
        Bf[p][g][kk] = f;
      }
    }

  // h0 + gate-n bias
  float hold[4][4];
  float bn[4];
#pragma unroll
  for (int p = 0; p < 4; ++p) {
    int j = jw + p * 16 + col;
    bn[p] = bhh[512 + j];
#pragma unroll
    for (int r = 0; r < 4; ++r) {
      int b = quad * 4 + r;
      float h = h0[(size_t)(b0 + b) * 256 + j];
      hold[p][r] = h;
      hA[0][(j >> 3) * 128 + b * 8 + (j & 7)] = (__fp16)h;
    }
  }
  __syncthreads();

  for (int i = 0; i < 512; ++i) {
    // Gi loads for this step (latency hidden under MFMA phase)
    uint2 gi[4][3];
#pragma unroll
    for (int p = 0; p < 4; ++p)
#pragma unroll
      for (int g = 0; g < 3; ++g) {
        size_t idx = (((size_t)i * 3 + g) * 256 + (jw + p * 16 + col)) * 32
                     + b0 + quad * 4;
        gi[p][g] = *(const uint2*)&Gi2[idx];
      }

    // MFMA phase: 12 independent acc chains x 8 k-steps
    f32x4 acc[4][3];
#pragma unroll
    for (int p = 0; p < 4; ++p)
#pragma unroll
      for (int g = 0; g < 3; ++g)
        acc[p][g] = (f32x4){0.f, 0.f, 0.f, 0.f};

    const __fp16* hbuf = hA[i & 1];
#pragma unroll
    for (int kk = 0; kk < 8; ++kk) {
      f16x8 a = *(const f16x8*)&hbuf[(kk * 4 + quad) * 128 + col * 8];
#pragma unroll
      for (int p = 0; p < 4; ++p)
#pragma unroll
        for (int g = 0; g < 3; ++g)
          acc[p][g] = __builtin_amdgcn_mfma_f32_16x16x32_f16(
              a, Bf[p][g][kk], acc[p][g], 0, 0, 0);
    }

    // epilogue: in-lane gate combine; C/D layout col=lane&15 (=j), row=quad*4+reg (=b)
    __fp16* hnext = hA[(i + 1) & 1];
#pragma unroll
    for (int p = 0; p < 4; ++p) {
      f16x4_t g0 = __builtin_bit_cast(f16x4_t, gi[p][0]);
      f16x4_t g1 = __builtin_bit_cast(f16x4_t, gi[p][1]);
      f16x4_t g2 = __builtin_bit_cast(f16x4_t, gi[p][2]);
      int j = jw + p * 16 + col;
#pragma unroll
      for (int r = 0; r < 4; ++r) {
        int b = quad * 4 + r;
        float rr = rcp_f(1.f + exp2_f(-LOG2E * ((float)g0[r] + acc[p][0][r])));
        float zz = rcp_f(1.f + exp2_f(-LOG2E * ((float)g1[r] + acc[p][1][r])));
        float na = fmaf(rr, acc[p][2][r] + bn[p], (float)g2[r]);
        float nn = fmaf(-2.f, rcp_f(1.f + exp2_f(C2 * na)), 1.f);  // tanh
        float h = fmaf(zz, hold[p][r] - nn, nn);
        hold[p][r] = h;
        out[((size_t)i * 32 + b0 + b) * 256 + j] = h;
        hnext[(j >> 3) * 128 + b * 8 + (j & 7)] = (__fp16)h;
      }
    }
    __syncthreads();
  }
}

// ---------------------------------------------------------------------------
extern "C" void kernel_launch(void* const* d_in, const int* in_sizes, int n_in,
                              void* d_out, int out_size, void* d_ws, size_t ws_size,
                              hipStream_t stream)
{
  const float* v   = (const float*)d_in[0];
  const float* h0  = (const float*)d_in[1];
  const float* Vv  = (const float*)d_in[2];
  const float* Wp  = (const float*)d_in[3];
  const float* Wp_ = (const float*)d_in[4];
  const float* Wih = (const float*)d_in[5];
  const float* Whh = (const float*)d_in[6];
  const float* bih = (const float*)d_in[7];
  const float* bhh = (const float*)d_in[8];
  float* out = (float*)d_out;
  float* ws  = (float*)d_ws;

  float* Eq = ws;
  float* Ev = ws + 4194304;
  float* S  = ws + 8388608;
  float* C  = ws;                          // reuse Eq (dead after score_k)
  __fp16* Gi2 = (__fp16*)(ws + 4194304);   // reuse Ev+S (dead after ctx_k)

  gemm_nt<<<dim3(4, 256), 256, 0, stream>>>(v, Wp,  nullptr, Eq, 256, 1);
  gemm_nt<<<dim3(4, 256), 256, 0, stream>>>(v, Wp_, nullptr, Ev, 256, 1);
  score_k<<<dim3(16, 8, 32), 256, 0, stream>>>(Eq, Ev, Vv, S);
  softmax_k<<<16384, 64, 0, stream>>>(S);
  ctx_k<<<dim3(4, 8, 32), 256, 0, stream>>>(S, v, C);
  gemm_gi<<<dim3(12, 256), 256, 0, stream>>>(C, Wih, bih, bhh, Gi2);
  gru_k<<<2, 256, 0, stream>>>(Gi2, Whh, bhh, h0, out);
}

// Round 7
// 1440.734 us; speedup vs baseline: 1.8458x; 1.8458x over previous
//
#include <hip/hip_runtime.h>
#include <stdint.h>

// L=512, B=32, D=H=256
// Workspace layout (floats):
//   Eq  [16384*256] @ 0         (exp2(C2*xq))
//   Ev  [16384*256] @ 4194304   (exp2(C2*xv))
//   S   [32*512*512] @ 8388608  (scores, then softmax in place)
//   C   [16384*256] @ 0         (context, reuses Eq region - dead after score_k)
//   Gi2 [f16, 16384*768] @ float-offset 4194304 (reuses Ev+S - dead after ctx_k)

#define C2    2.8853900817779268f   // 2*log2(e)
#define LOG2E 1.4426950408889634f

typedef __fp16 f16x2 __attribute__((ext_vector_type(2)));
typedef __fp16 f16x4_t __attribute__((ext_vector_type(4)));
typedef __fp16 f16x8 __attribute__((ext_vector_type(8)));
typedef float f32x4 __attribute__((ext_vector_type(4)));

static __device__ __forceinline__ float rcp_f(float x)  { return __builtin_amdgcn_rcpf(x); }
static __device__ __forceinline__ float exp2_f(float x) { return __builtin_amdgcn_exp2f(x); }

// ---------------------------------------------------------------------------
// out[m][n] = epilogue( sum_d A[m][d] * W[n][d] ),  K = 256 fixed
// expmode=1: out = exp2(C2*acc); expmode=0: out = acc + bias[n]
// ---------------------------------------------------------------------------
__global__ __launch_bounds__(256) void gemm_nt(
    const float* __restrict__ A, const float* __restrict__ W,
    const float* __restrict__ bias, float* __restrict__ out,
    int N, int expmode)
{
  __shared__ __align__(16) float As[32][68];
  __shared__ __align__(16) float Ws[32][68];
  const int t = threadIdx.x;
  const int tx = t & 15, ty = t >> 4;
  const int n0 = blockIdx.x * 64, m0 = blockIdx.y * 64;
  float acc[4][4] = {};

  for (int k0 = 0; k0 < 256; k0 += 32) {
#pragma unroll
    for (int s = 0; s < 2; ++s) {
      int f = t + s * 256;
      int row = f >> 3, kq = f & 7;
      float4 a = *(const float4*)&A[(size_t)(m0 + row) * 256 + k0 + kq * 4];
      float4 w = *(const float4*)&W[(size_t)(n0 + row) * 256 + k0 + kq * 4];
      As[kq * 4 + 0][row] = a.x; As[kq * 4 + 1][row] = a.y;
      As[kq * 4 + 2][row] = a.z; As[kq * 4 + 3][row] = a.w;
      Ws[kq * 4 + 0][row] = w.x; Ws[kq * 4 + 1][row] = w.y;
      Ws[kq * 4 + 2][row] = w.z; Ws[kq * 4 + 3][row] = w.w;
    }
    __syncthreads();
#pragma unroll
    for (int kk = 0; kk < 32; ++kk) {
      float4 a4 = *(const float4*)&As[kk][ty * 4];
      float4 b4 = *(const float4*)&Ws[kk][tx * 4];
      float av[4] = {a4.x, a4.y, a4.z, a4.w};
      float bv[4] = {b4.x, b4.y, b4.z, b4.w};
#pragma unroll
      for (int r = 0; r < 4; ++r)
#pragma unroll
        for (int c = 0; c < 4; ++c)
          acc[r][c] = fmaf(av[r], bv[c], acc[r][c]);
    }
    __syncthreads();
  }

#pragma unroll
  for (int r = 0; r < 4; ++r) {
    float4 o;
    if (expmode) {
      o.x = exp2_f(C2 * acc[r][0]); o.y = exp2_f(C2 * acc[r][1]);
      o.z = exp2_f(C2 * acc[r][2]); o.w = exp2_f(C2 * acc[r][3]);
    } else {
      float4 bb = *(const float4*)&bias[n0 + tx * 4];
      o.x = acc[r][0] + bb.x; o.y = acc[r][1] + bb.y;
      o.z = acc[r][2] + bb.z; o.w = acc[r][3] + bb.w;
    }
    *(float4*)&out[(size_t)(m0 + ty * 4 + r) * N + n0 + tx * 4] = o;
  }
}

// ---------------------------------------------------------------------------
// Gi gemm: G = C @ Wih^T + (bih + bhh folded for gates r,z; bih only for n).
// Output packed f16 in transposed layout Gi2[i][g][j][b]  (b innermost, 32).
// ---------------------------------------------------------------------------
__global__ __launch_bounds__(256) void gemm_gi(
    const float* __restrict__ A, const float* __restrict__ W,
    const float* __restrict__ bih, const float* __restrict__ bhh,
    __fp16* __restrict__ G)
{
  __shared__ __align__(16) float As[32][68];
  __shared__ __align__(16) float Ws[32][68];
  const int t = threadIdx.x;
  const int tx = t & 15, ty = t >> 4;
  const int n0 = blockIdx.x * 64, m0 = blockIdx.y * 64;
  float acc[4][4] = {};

  for (int k0 = 0; k0 < 256; k0 += 32) {
#pragma unroll
    for (int s = 0; s < 2; ++s) {
      int f = t + s * 256;
      int row = f >> 3, kq = f & 7;
      float4 a = *(const float4*)&A[(size_t)(m0 + row) * 256 + k0 + kq * 4];
      float4 w = *(const float4*)&W[(size_t)(n0 + row) * 256 + k0 + kq * 4];
      As[kq * 4 + 0][row] = a.x; As[kq * 4 + 1][row] = a.y;
      As[kq * 4 + 2][row] = a.z; As[kq * 4 + 3][row] = a.w;
      Ws[kq * 4 + 0][row] = w.x; Ws[kq * 4 + 1][row] = w.y;
      Ws[kq * 4 + 2][row] = w.z; Ws[kq * 4 + 3][row] = w.w;
    }
    __syncthreads();
#pragma unroll
    for (int kk = 0; kk < 32; ++kk) {
      float4 a4 = *(const float4*)&As[kk][ty * 4];
      float4 b4 = *(const float4*)&Ws[kk][tx * 4];
      float av[4] = {a4.x, a4.y, a4.z, a4.w};
      float bv[4] = {b4.x, b4.y, b4.z, b4.w};
#pragma unroll
      for (int r = 0; r < 4; ++r)
#pragma unroll
        for (int c = 0; c < 4; ++c)
          acc[r][c] = fmaf(av[r], bv[c], acc[r][c]);
    }
    __syncthreads();
  }

  float bias[4];
#pragma unroll
  for (int c = 0; c < 4; ++c) {
    int n = n0 + tx * 4 + c;
    bias[c] = bih[n] + (n < 512 ? bhh[n] : 0.f);
  }
#pragma unroll
  for (int r = 0; r < 4; ++r) {
    int m = m0 + ty * 4 + r;
    int i = m >> 5, b = m & 31;
#pragma unroll
    for (int c = 0; c < 4; ++c) {
      int n = n0 + tx * 4 + c;
      int g = n >> 8, j = n & 255;
      G[(((size_t)i * 3 + g) * 256 + j) * 32 + b] = (__fp16)(acc[r][c] + bias[c]);
    }
  }
}

// ---------------------------------------------------------------------------
// S[b][i][l] = -2 * sum_h Vvec[b][h] * rcp(1 + Eq[i][b][h]*Ev[l][b][h])
// ---------------------------------------------------------------------------
__global__ __launch_bounds__(256) void score_k(
    const float* __restrict__ Eq, const float* __restrict__ Ev,
    const float* __restrict__ Vvec, float* __restrict__ S)
{
  __shared__ __align__(16) float Eqs[64][68];
  __shared__ __align__(16) float Evs[32][68];
  __shared__ __align__(16) float Vs[256];
  const int t = threadIdx.x;
  const int tx = t & 15, ty = t >> 4;
  const int l0 = blockIdx.x * 32;
  const int i0 = blockIdx.y * 64;
  const int b  = blockIdx.z;

  Vs[t] = -2.0f * Vvec[b * 256 + t];
  float acc[4][2] = {};

  for (int st = 0; st < 4; ++st) {
    const int h0 = st * 64;
#pragma unroll
    for (int s = 0; s < 4; ++s) {
      int f = t + s * 256;
      int row = f >> 4, cq = f & 15;
      *(float4*)&Eqs[row][cq * 4] =
          *(const float4*)&Eq[((size_t)(i0 + row) * 32 + b) * 256 + h0 + cq * 4];
    }
#pragma unroll
    for (int s = 0; s < 2; ++s) {
      int f = t + s * 256;
      int row = f >> 4, cq = f & 15;
      *(float4*)&Evs[row][cq * 4] =
          *(const float4*)&Ev[((size_t)(l0 + row) * 32 + b) * 256 + h0 + cq * 4];
    }
    __syncthreads();
#pragma unroll 4
    for (int k4 = 0; k4 < 16; ++k4) {
      float4 vh = *(const float4*)&Vs[h0 + k4 * 4];
      float4 e0 = *(const float4*)&Evs[tx][k4 * 4];
      float4 e1 = *(const float4*)&Evs[tx + 16][k4 * 4];
#pragma unroll
      for (int r = 0; r < 4; ++r) {
        float4 eq = *(const float4*)&Eqs[ty * 4 + r][k4 * 4];
        acc[r][0] += vh.x * rcp_f(fmaf(eq.x, e0.x, 1.0f));
        acc[r][0] += vh.y * rcp_f(fmaf(eq.y, e0.y, 1.0f));
        acc[r][0] += vh.z * rcp_f(fmaf(eq.z, e0.z, 1.0f));
        acc[r][0] += vh.w * rcp_f(fmaf(eq.w, e0.w, 1.0f));
        acc[r][1] += vh.x * rcp_f(fmaf(eq.x, e1.x, 1.0f));
        acc[r][1] += vh.y * rcp_f(fmaf(eq.y, e1.y, 1.0f));
        acc[r][1] += vh.z * rcp_f(fmaf(eq.z, e1.z, 1.0f));
        acc[r][1] += vh.w * rcp_f(fmaf(eq.w, e1.w, 1.0f));
      }
    }
    __syncthreads();
  }

#pragma unroll
  for (int r = 0; r < 4; ++r) {
    float* ps = &S[((size_t)b * 512 + i0 + ty * 4 + r) * 512 + l0];
    ps[tx]      = acc[r][0];
    ps[tx + 16] = acc[r][1];
  }
}

// ---------------------------------------------------------------------------
// In-place softmax over last dim (512) of S viewed as [16384][512].
// ---------------------------------------------------------------------------
__global__ __launch_bounds__(64) void softmax_k(float* __restrict__ S)
{
  const int t = threadIdx.x;
  float* row = &S[(size_t)blockIdx.x * 512];
  float x[8];
  float m = -1e30f;
#pragma unroll
  for (int u = 0; u < 8; ++u) { x[u] = row[t + u * 64]; m = fmaxf(m, x[u]); }
#pragma unroll
  for (int o = 32; o; o >>= 1) m = fmaxf(m, __shfl_xor(m, o, 64));
  float sum = 0.f;
#pragma unroll
  for (int u = 0; u < 8; ++u) { x[u] = exp2_f(LOG2E * (x[u] - m)); sum += x[u]; }
#pragma unroll
  for (int o = 32; o; o >>= 1) sum += __shfl_xor(sum, o, 64);
  float inv = rcp_f(sum);
#pragma unroll
  for (int u = 0; u < 8; ++u) row[t + u * 64] = x[u] * inv;
}

// ---------------------------------------------------------------------------
// C[i][b][d] = sum_l A[b][i][l] * v[l][b][d]
// ---------------------------------------------------------------------------
__global__ __launch_bounds__(256) void ctx_k(
    const float* __restrict__ Aw, const float* __restrict__ v,
    float* __restrict__ C)
{
  __shared__ __align__(16) float As[32][68];
  __shared__ __align__(16) float Vs[32][68];
  const int t = threadIdx.x, tx = t & 15, ty = t >> 4;
  const int d0 = blockIdx.x * 64, i0 = blockIdx.y * 64, b = blockIdx.z;
  float acc[4][4] = {};

  for (int l0 = 0; l0 < 512; l0 += 32) {
#pragma unroll
    for (int s = 0; s < 2; ++s) {
      int f = t + s * 256;
      int row = f >> 3, lq = f & 7;
      float4 a = *(const float4*)&Aw[((size_t)b * 512 + i0 + row) * 512 + l0 + lq * 4];
      As[lq * 4 + 0][row] = a.x; As[lq * 4 + 1][row] = a.y;
      As[lq * 4 + 2][row] = a.z; As[lq * 4 + 3][row] = a.w;
    }
#pragma unroll
    for (int s = 0; s < 2; ++s) {
      int f = t + s * 256;
      int row = f >> 4, dq = f & 15;
      *(float4*)&Vs[row][dq * 4] =
          *(const float4*)&v[((size_t)(l0 + row) * 32 + b) * 256 + d0 + dq * 4];
    }
    __syncthreads();
#pragma unroll
    for (int kk = 0; kk < 32; ++kk) {
      float4 a4 = *(const float4*)&As[kk][ty * 4];
      float4 b4 = *(const float4*)&Vs[kk][tx * 4];
      float av[4] = {a4.x, a4.y, a4.z, a4.w};
      float bv[4] = {b4.x, b4.y, b4.z, b4.w};
#pragma unroll
      for (int r = 0; r < 4; ++r)
#pragma unroll
        for (int c = 0; c < 4; ++c)
          acc[r][c] = fmaf(av[r], bv[c], acc[r][c]);
    }
    __syncthreads();
  }

#pragma unroll
  for (int r = 0; r < 4; ++r) {
    float4 o = {acc[r][0], acc[r][1], acc[r][2], acc[r][3]};
    *(float4*)&C[((size_t)(i0 + ty * 4 + r) * 32 + b) * 256 + d0 + tx * 4] = o;
  }
}

// ---------------------------------------------------------------------------
// MFMA GRU. 2 blocks x 512 threads (8 waves, 2/SIMD). Block = 16 batches.
// R6's math (verified: absmax 0.0078) but HALF the per-thread weight load:
// each wave owns 2 gate-TRIPLETS (j-tiles {j, j+256, j+512}), so Bf = 192
// dwords/thread -> fits 128-arch + 256-AGPR unified budget with room for
// acc/gi/temps (R6: 520 dwords > 512 budget -> scratch spill -> 2101 us).
// MFMA reads AGPR-resident B operands natively (no accvgpr_read tax).
// h LDS buffer row stride 280 halfwords: write aliasing 2-way (free),
// b128 A-frag reads 2-way. One barrier/step; Gi prefetched under MFMA.
// ---------------------------------------------------------------------------
__global__ __launch_bounds__(512, 1) void gru_k(
    const __fp16* __restrict__ Gi2, const float* __restrict__ Whh,
    const float* __restrict__ bhh, const float* __restrict__ h0,
    float* __restrict__ out)
{
  __shared__ __align__(16) __fp16 hA[2][16 * 280];
  const int t = threadIdx.x, wave = t >> 6, lane = t & 63;
  const int quad = lane >> 4, col = lane & 15;
  const int b0 = blockIdx.x * 16;
  const int jw = wave * 32;

  // B fragments: Bf[p][g][kk], lane holds B[k=kk*32+quad*8+jj][n=col] =
  // Whh[g*256 + jw + p*16 + col][kk*32 + quad*8 + jj], jj=0..7
  f16x8 Bf[2][3][8];
#pragma unroll
  for (int p = 0; p < 2; ++p)
#pragma unroll
    for (int g = 0; g < 3; ++g) {
      const float* wrow = &Whh[(size_t)(g * 256 + jw + p * 16 + col) * 256];
#pragma unroll
      for (int kk = 0; kk < 8; ++kk) {
        const float4* wp = (const float4*)&wrow[kk * 32 + quad * 8];
        float4 w0 = wp[0], w1 = wp[1];
        f16x8 f;
        f[0] = (__fp16)w0.x; f[1] = (__fp16)w0.y;
        f[2] = (__fp16)w0.z; f[3] = (__fp16)w0.w;
        f[4] = (__fp16)w1.x; f[5] = (__fp16)w1.y;
        f[6] = (__fp16)w1.z; f[7] = (__fp16)w1.w;
        Bf[p][g][kk] = f;
      }
    }

  // h0 + gate-n bias; lane owns (b = quad*4+r, j = jw + p*16 + col)
  float hold[2][4];
  float bn[2];
#pragma unroll
  for (int p = 0; p < 2; ++p) {
    int j = jw + p * 16 + col;
    bn[p] = bhh[512 + j];
#pragma unroll
    for (int r = 0; r < 4; ++r) {
      int b = quad * 4 + r;
      float h = h0[(size_t)(b0 + b) * 256 + j];
      hold[p][r] = h;
      hA[0][b * 280 + j] = (__fp16)h;
    }
  }
  __syncthreads();

  for (int i = 0; i < 512; ++i) {
    // Gi loads for this step (latency hidden under MFMA phase)
    uint2 gi[2][3];
#pragma unroll
    for (int p = 0; p < 2; ++p)
#pragma unroll
      for (int g = 0; g < 3; ++g) {
        size_t idx = (((size_t)i * 3 + g) * 256 + (jw + p * 16 + col)) * 32
                     + b0 + quad * 4;
        gi[p][g] = *(const uint2*)&Gi2[idx];
      }

    // MFMA phase: 6 independent acc chains x 8 k-steps
    f32x4 acc[2][3];
#pragma unroll
    for (int p = 0; p < 2; ++p)
#pragma unroll
      for (int g = 0; g < 3; ++g)
        acc[p][g] = (f32x4){0.f, 0.f, 0.f, 0.f};

    const __fp16* hbuf = hA[i & 1];
#pragma unroll
    for (int kk = 0; kk < 8; ++kk) {
      // A[m=col][k=kk*32+quad*8+jj] = h[b=col][j=k]
      f16x8 a = *(const f16x8*)&hbuf[col * 280 + kk * 32 + quad * 8];
#pragma unroll
      for (int p = 0; p < 2; ++p)
#pragma unroll
        for (int g = 0; g < 3; ++g)
          acc[p][g] = __builtin_amdgcn_mfma_f32_16x16x32_f16(
              a, Bf[p][g][kk], acc[p][g], 0, 0, 0);
    }

    // epilogue: C/D layout col=lane&15 (=j), row=quad*4+reg (=b); in-lane gates
    __fp16* hnext = hA[(i + 1) & 1];
#pragma unroll
    for (int p = 0; p < 2; ++p) {
      f16x4_t g0 = __builtin_bit_cast(f16x4_t, gi[p][0]);
      f16x4_t g1 = __builtin_bit_cast(f16x4_t, gi[p][1]);
      f16x4_t g2 = __builtin_bit_cast(f16x4_t, gi[p][2]);
      int j = jw + p * 16 + col;
#pragma unroll
      for (int r = 0; r < 4; ++r) {
        int b = quad * 4 + r;
        float rr = rcp_f(1.f + exp2_f(-LOG2E * ((float)g0[r] + acc[p][0][r])));
        float zz = rcp_f(1.f + exp2_f(-LOG2E * ((float)g1[r] + acc[p][1][r])));
        float na = fmaf(rr, acc[p][2][r] + bn[p], (float)g2[r]);
        float nn = fmaf(-2.f, rcp_f(1.f + exp2_f(C2 * na)), 1.f);  // tanh
        float h = fmaf(zz, hold[p][r] - nn, nn);
        hold[p][r] = h;
        out[((size_t)i * 32 + b0 + b) * 256 + j] = h;
        hnext[b * 280 + j] = (__fp16)h;
      }
    }
    __syncthreads();
  }
}

// ---------------------------------------------------------------------------
extern "C" void kernel_launch(void* const* d_in, const int* in_sizes, int n_in,
                              void* d_out, int out_size, void* d_ws, size_t ws_size,
                              hipStream_t stream)
{
  const float* v   = (const float*)d_in[0];
  const float* h0  = (const float*)d_in[1];
  const float* Vv  = (const float*)d_in[2];
  const float* Wp  = (const float*)d_in[3];
  const float* Wp_ = (const float*)d_in[4];
  const float* Wih = (const float*)d_in[5];
  const float* Whh = (const float*)d_in[6];
  const float* bih = (const float*)d_in[7];
  const float* bhh = (const float*)d_in[8];
  float* out = (float*)d_out;
  float* ws  = (float*)d_ws;

  float* Eq = ws;
  float* Ev = ws + 4194304;
  float* S  = ws + 8388608;
  float* C  = ws;                          // reuse Eq (dead after score_k)
  __fp16* Gi2 = (__fp16*)(ws + 4194304);   // reuse Ev+S (dead after ctx_k)

  gemm_nt<<<dim3(4, 256), 256, 0, stream>>>(v, Wp,  nullptr, Eq, 256, 1);
  gemm_nt<<<dim3(4, 256), 256, 0, stream>>>(v, Wp_, nullptr, Ev, 256, 1);
  score_k<<<dim3(16, 8, 32), 256, 0, stream>>>(Eq, Ev, Vv, S);
  softmax_k<<<16384, 64, 0, stream>>>(S);
  ctx_k<<<dim3(4, 8, 32), 256, 0, stream>>>(S, v, C);
  gemm_gi<<<dim3(12, 256), 256, 0, stream>>>(C, Wih, bih, bhh, Gi2);
  gru_k<<<2, 512, 0, stream>>>(Gi2, Whh, bhh, h0, out);
}

// Round 8
// 1057.851 us; speedup vs baseline: 2.5139x; 1.3619x over previous
//
#include <hip/hip_runtime.h>
#include <stdint.h>

// L=512, B=32, D=H=256
// Workspace layout (floats):
//   Eq  [16384*256] @ 0         (exp2(C2*xq))
//   Ev  [16384*256] @ 4194304   (exp2(C2*xv))
//   S   [32*512*512] @ 8388608  (scores, then softmax in place)
//   C   [16384*256] @ 0         (context, reuses Eq region - dead after score_k)
//   Gi2 [f16, 16384*768] @ float-offset 4194304, layout [i*32+b][g*256+j]

#define C2    2.8853900817779268f   // 2*log2(e)
#define LOG2E 1.4426950408889634f

typedef __fp16 f16x2 __attribute__((ext_vector_type(2)));
typedef __fp16 f16x4_t __attribute__((ext_vector_type(4)));
typedef __fp16 f16x8 __attribute__((ext_vector_type(8)));
typedef float f32x4 __attribute__((ext_vector_type(4)));

static __device__ __forceinline__ float rcp_f(float x)  { return __builtin_amdgcn_rcpf(x); }
static __device__ __forceinline__ float exp2_f(float x) { return __builtin_amdgcn_exp2f(x); }

// ---------------------------------------------------------------------------
// out[m][n] = epilogue( sum_d A[m][d] * W[n][d] ),  K = 256 fixed
// expmode=1: out = exp2(C2*acc); expmode=0: out = acc + bias[n]
// ---------------------------------------------------------------------------
__global__ __launch_bounds__(256) void gemm_nt(
    const float* __restrict__ A, const float* __restrict__ W,
    const float* __restrict__ bias, float* __restrict__ out,
    int N, int expmode)
{
  __shared__ __align__(16) float As[32][68];
  __shared__ __align__(16) float Ws[32][68];
  const int t = threadIdx.x;
  const int tx = t & 15, ty = t >> 4;
  const int n0 = blockIdx.x * 64, m0 = blockIdx.y * 64;
  float acc[4][4] = {};

  for (int k0 = 0; k0 < 256; k0 += 32) {
#pragma unroll
    for (int s = 0; s < 2; ++s) {
      int f = t + s * 256;
      int row = f >> 3, kq = f & 7;
      float4 a = *(const float4*)&A[(size_t)(m0 + row) * 256 + k0 + kq * 4];
      float4 w = *(const float4*)&W[(size_t)(n0 + row) * 256 + k0 + kq * 4];
      As[kq * 4 + 0][row] = a.x; As[kq * 4 + 1][row] = a.y;
      As[kq * 4 + 2][row] = a.z; As[kq * 4 + 3][row] = a.w;
      Ws[kq * 4 + 0][row] = w.x; Ws[kq * 4 + 1][row] = w.y;
      Ws[kq * 4 + 2][row] = w.z; Ws[kq * 4 + 3][row] = w.w;
    }
    __syncthreads();
#pragma unroll
    for (int kk = 0; kk < 32; ++kk) {
      float4 a4 = *(const float4*)&As[kk][ty * 4];
      float4 b4 = *(const float4*)&Ws[kk][tx * 4];
      float av[4] = {a4.x, a4.y, a4.z, a4.w};
      float bv[4] = {b4.x, b4.y, b4.z, b4.w};
#pragma unroll
      for (int r = 0; r < 4; ++r)
#pragma unroll
        for (int c = 0; c < 4; ++c)
          acc[r][c] = fmaf(av[r], bv[c], acc[r][c]);
    }
    __syncthreads();
  }

#pragma unroll
  for (int r = 0; r < 4; ++r) {
    float4 o;
    if (expmode) {
      o.x = exp2_f(C2 * acc[r][0]); o.y = exp2_f(C2 * acc[r][1]);
      o.z = exp2_f(C2 * acc[r][2]); o.w = exp2_f(C2 * acc[r][3]);
    } else {
      float4 bb = *(const float4*)&bias[n0 + tx * 4];
      o.x = acc[r][0] + bb.x; o.y = acc[r][1] + bb.y;
      o.z = acc[r][2] + bb.z; o.w = acc[r][3] + bb.w;
    }
    *(float4*)&out[(size_t)(m0 + ty * 4 + r) * N + n0 + tx * 4] = o;
  }
}

// ---------------------------------------------------------------------------
// Gi gemm: G = C @ Wih^T + (bih + bhh folded for gates r,z; bih only for n).
// Output packed f16, natural layout G[m][n], m = i*32+b, n = g*256+j.
// ---------------------------------------------------------------------------
__global__ __launch_bounds__(256) void gemm_gi(
    const float* __restrict__ A, const float* __restrict__ W,
    const float* __restrict__ bih, const float* __restrict__ bhh,
    __fp16* __restrict__ G)
{
  __shared__ __align__(16) float As[32][68];
  __shared__ __align__(16) float Ws[32][68];
  const int t = threadIdx.x;
  const int tx = t & 15, ty = t >> 4;
  const int n0 = blockIdx.x * 64, m0 = blockIdx.y * 64;
  float acc[4][4] = {};

  for (int k0 = 0; k0 < 256; k0 += 32) {
#pragma unroll
    for (int s = 0; s < 2; ++s) {
      int f = t + s * 256;
      int row = f >> 3, kq = f & 7;
      float4 a = *(const float4*)&A[(size_t)(m0 + row) * 256 + k0 + kq * 4];
      float4 w = *(const float4*)&W[(size_t)(n0 + row) * 256 + k0 + kq * 4];
      As[kq * 4 + 0][row] = a.x; As[kq * 4 + 1][row] = a.y;
      As[kq * 4 + 2][row] = a.z; As[kq * 4 + 3][row] = a.w;
      Ws[kq * 4 + 0][row] = w.x; Ws[kq * 4 + 1][row] = w.y;
      Ws[kq * 4 + 2][row] = w.z; Ws[kq * 4 + 3][row] = w.w;
    }
    __syncthreads();
#pragma unroll
    for (int kk = 0; kk < 32; ++kk) {
      float4 a4 = *(const float4*)&As[kk][ty * 4];
      float4 b4 = *(const float4*)&Ws[kk][tx * 4];
      float av[4] = {a4.x, a4.y, a4.z, a4.w};
      float bv[4] = {b4.x, b4.y, b4.z, b4.w};
#pragma unroll
      for (int r = 0; r < 4; ++r)
#pragma unroll
        for (int c = 0; c < 4; ++c)
          acc[r][c] = fmaf(av[r], bv[c], acc[r][c]);
    }
    __syncthreads();
  }

  float bias[4];
#pragma unroll
  for (int c = 0; c < 4; ++c) {
    int n = n0 + tx * 4 + c;
    bias[c] = bih[n] + (n < 512 ? bhh[n] : 0.f);
  }
#pragma unroll
  for (int r = 0; r < 4; ++r) {
    int m = m0 + ty * 4 + r;
    f16x4_t o;
#pragma unroll
    for (int c = 0; c < 4; ++c) o[c] = (__fp16)(acc[r][c] + bias[c]);
    *(f16x4_t*)&G[(size_t)m * 768 + n0 + tx * 4] = o;
  }
}

// ---------------------------------------------------------------------------
// S[b][i][l] = -2 * sum_h Vvec[b][h] * rcp(1 + Eq[i][b][h]*Ev[l][b][h])
// ---------------------------------------------------------------------------
__global__ __launch_bounds__(256) void score_k(
    const float* __restrict__ Eq, const float* __restrict__ Ev,
    const float* __restrict__ Vvec, float* __restrict__ S)
{
  __shared__ __align__(16) float Eqs[64][68];
  __shared__ __align__(16) float Evs[32][68];
  __shared__ __align__(16) float Vs[256];
  const int t = threadIdx.x;
  const int tx = t & 15, ty = t >> 4;
  const int l0 = blockIdx.x * 32;
  const int i0 = blockIdx.y * 64;
  const int b  = blockIdx.z;

  Vs[t] = -2.0f * Vvec[b * 256 + t];
  float acc[4][2] = {};

  for (int st = 0; st < 4; ++st) {
    const int h0 = st * 64;
#pragma unroll
    for (int s = 0; s < 4; ++s) {
      int f = t + s * 256;
      int row = f >> 4, cq = f & 15;
      *(float4*)&Eqs[row][cq * 4] =
          *(const float4*)&Eq[((size_t)(i0 + row) * 32 + b) * 256 + h0 + cq * 4];
    }
#pragma unroll
    for (int s = 0; s < 2; ++s) {
      int f = t + s * 256;
      int row = f >> 4, cq = f & 15;
      *(float4*)&Evs[row][cq * 4] =
          *(const float4*)&Ev[((size_t)(l0 + row) * 32 + b) * 256 + h0 + cq * 4];
    }
    __syncthreads();
#pragma unroll 4
    for (int k4 = 0; k4 < 16; ++k4) {
      float4 vh = *(const float4*)&Vs[h0 + k4 * 4];
      float4 e0 = *(const float4*)&Evs[tx][k4 * 4];
      float4 e1 = *(const float4*)&Evs[tx + 16][k4 * 4];
#pragma unroll
      for (int r = 0; r < 4; ++r) {
        float4 eq = *(const float4*)&Eqs[ty * 4 + r][k4 * 4];
        acc[r][0] += vh.x * rcp_f(fmaf(eq.x, e0.x, 1.0f));
        acc[r][0] += vh.y * rcp_f(fmaf(eq.y, e0.y, 1.0f));
        acc[r][0] += vh.z * rcp_f(fmaf(eq.z, e0.z, 1.0f));
        acc[r][0] += vh.w * rcp_f(fmaf(eq.w, e0.w, 1.0f));
        acc[r][1] += vh.x * rcp_f(fmaf(eq.x, e1.x, 1.0f));
        acc[r][1] += vh.y * rcp_f(fmaf(eq.y, e1.y, 1.0f));
        acc[r][1] += vh.z * rcp_f(fmaf(eq.z, e1.z, 1.0f));
        acc[r][1] += vh.w * rcp_f(fmaf(eq.w, e1.w, 1.0f));
      }
    }
    __syncthreads();
  }

#pragma unroll
  for (int r = 0; r < 4; ++r) {
    float* ps = &S[((size_t)b * 512 + i0 + ty * 4 + r) * 512 + l0];
    ps[tx]      = acc[r][0];
    ps[tx + 16] = acc[r][1];
  }
}

// ---------------------------------------------------------------------------
// In-place softmax over last dim (512) of S viewed as [16384][512].
// ---------------------------------------------------------------------------
__global__ __launch_bounds__(64) void softmax_k(float* __restrict__ S)
{
  const int t = threadIdx.x;
  float* row = &S[(size_t)blockIdx.x * 512];
  float x[8];
  float m = -1e30f;
#pragma unroll
  for (int u = 0; u < 8; ++u) { x[u] = row[t + u * 64]; m = fmaxf(m, x[u]); }
#pragma unroll
  for (int o = 32; o; o >>= 1) m = fmaxf(m, __shfl_xor(m, o, 64));
  float sum = 0.f;
#pragma unroll
  for (int u = 0; u < 8; ++u) { x[u] = exp2_f(LOG2E * (x[u] - m)); sum += x[u]; }
#pragma unroll
  for (int o = 32; o; o >>= 1) sum += __shfl_xor(sum, o, 64);
  float inv = rcp_f(sum);
#pragma unroll
  for (int u = 0; u < 8; ++u) row[t + u * 64] = x[u] * inv;
}

// ---------------------------------------------------------------------------
// C[i][b][d] = sum_l A[b][i][l] * v[l][b][d]
// ---------------------------------------------------------------------------
__global__ __launch_bounds__(256) void ctx_k(
    const float* __restrict__ Aw, const float* __restrict__ v,
    float* __restrict__ C)
{
  __shared__ __align__(16) float As[32][68];
  __shared__ __align__(16) float Vs[32][68];
  const int t = threadIdx.x, tx = t & 15, ty = t >> 4;
  const int d0 = blockIdx.x * 64, i0 = blockIdx.y * 64, b = blockIdx.z;
  float acc[4][4] = {};

  for (int l0 = 0; l0 < 512; l0 += 32) {
#pragma unroll
    for (int s = 0; s < 2; ++s) {
      int f = t + s * 256;
      int row = f >> 3, lq = f & 7;
      float4 a = *(const float4*)&Aw[((size_t)b * 512 + i0 + row) * 512 + l0 + lq * 4];
      As[lq * 4 + 0][row] = a.x; As[lq * 4 + 1][row] = a.y;
      As[lq * 4 + 2][row] = a.z; As[lq * 4 + 3][row] = a.w;
    }
#pragma unroll
    for (int s = 0; s < 2; ++s) {
      int f = t + s * 256;
      int row = f >> 4, dq = f & 15;
      *(float4*)&Vs[row][dq * 4] =
          *(const float4*)&v[((size_t)(l0 + row) * 32 + b) * 256 + d0 + dq * 4];
    }
    __syncthreads();
#pragma unroll
    for (int kk = 0; kk < 32; ++kk) {
      float4 a4 = *(const float4*)&As[kk][ty * 4];
      float4 b4 = *(const float4*)&Vs[kk][tx * 4];
      float av[4] = {a4.x, a4.y, a4.z, a4.w};
      float bv[4] = {b4.x, b4.y, b4.z, b4.w};
#pragma unroll
      for (int r = 0; r < 4; ++r)
#pragma unroll
        for (int c = 0; c < 4; ++c)
          acc[r][c] = fmaf(av[r], bv[c], acc[r][c]);
    }
    __syncthreads();
  }

#pragma unroll
  for (int r = 0; r < 4; ++r) {
    float4 o = {acc[r][0], acc[r][1], acc[r][2], acc[r][3]};
    *(float4*)&C[((size_t)(i0 + ty * 4 + r) * 32 + b) * 256 + d0 + tx * 4] = o;
  }
}

// ---------------------------------------------------------------------------
// MFMA GRU, ONE BATCH PER BLOCK (32 blocks x 512 threads). R7 was
// Gi-bandwidth-bound: 2 blocks = 2 CUs streaming 25 MB of Gi (~2400 cyc/step).
// Now Gi/CU/step = 1.5 KB (~150 cyc), prefetched one step ahead.
// Same verified MFMA math; h is BROADCAST into all 16 A-rows via a uniform
// ds_read_b128 (per-quad address, conflict-free) -> every C row equals
// gh[j]; all lanes run the epilogue on acc[..][0], quad-0 lanes write.
// Wave owns 2 gate-triplets: Bf = 192 dwords/thread (AGPR-resident, MFMA
// reads natively; R7-proven no-spill shape). One barrier/step.
// ---------------------------------------------------------------------------
__global__ __launch_bounds__(512, 1) void gru_k(
    const __fp16* __restrict__ Gi2, const float* __restrict__ Whh,
    const float* __restrict__ bhh, const float* __restrict__ h0,
    float* __restrict__ out)
{
  __shared__ __align__(16) __fp16 hA[2][256];
  const int t = threadIdx.x, wave = t >> 6, lane = t & 63;
  const int quad = lane >> 4, col = lane & 15;
  const int b = blockIdx.x;          // one batch per block
  const int jw = wave * 32;

  // B fragments: Bf[p][g][kk], lane holds B[k=kk*32+quad*8+jj][n=col] =
  // Whh[g*256 + jw + p*16 + col][kk*32 + quad*8 + jj], jj=0..7
  f16x8 Bf[2][3][8];
#pragma unroll
  for (int p = 0; p < 2; ++p)
#pragma unroll
    for (int g = 0; g < 3; ++g) {
      const float* wrow = &Whh[(size_t)(g * 256 + jw + p * 16 + col) * 256];
#pragma unroll
      for (int kk = 0; kk < 8; ++kk) {
        const float4* wp = (const float4*)&wrow[kk * 32 + quad * 8];
        float4 w0 = wp[0], w1 = wp[1];
        f16x8 f;
        f[0] = (__fp16)w0.x; f[1] = (__fp16)w0.y;
        f[2] = (__fp16)w0.z; f[3] = (__fp16)w0.w;
        f[4] = (__fp16)w1.x; f[5] = (__fp16)w1.y;
        f[6] = (__fp16)w1.z; f[7] = (__fp16)w1.w;
        Bf[p][g][kk] = f;
      }
    }

  // h0 + gate-n bias; lane's j = jw + p*16 + col
  float hold[2];
  float bn[2];
#pragma unroll
  for (int p = 0; p < 2; ++p) {
    int j = jw + p * 16 + col;
    bn[p] = bhh[512 + j];
    float h = h0[(size_t)b * 256 + j];
    hold[p] = h;
    if (quad == 0) hA[0][j] = (__fp16)h;
  }
  __syncthreads();

  // Gi prefetch for step 0
  __fp16 gcur[2][3];
#pragma unroll
  for (int p = 0; p < 2; ++p)
#pragma unroll
    for (int g = 0; g < 3; ++g)
      gcur[p][g] = Gi2[(size_t)b * 768 + g * 256 + jw + p * 16 + col];

  for (int i = 0; i < 512; ++i) {
    // prefetch Gi for next step (hidden under MFMA phase)
    __fp16 gnext[2][3];
    {
      int ip = (i + 1 < 512) ? (i + 1) : 511;
#pragma unroll
      for (int p = 0; p < 2; ++p)
#pragma unroll
        for (int g = 0; g < 3; ++g)
          gnext[p][g] =
              Gi2[(size_t)(ip * 32 + b) * 768 + g * 256 + jw + p * 16 + col];
    }

    // MFMA phase: 6 independent chains x 8 k-steps; A = h broadcast to all rows
    f32x4 acc[2][3];
#pragma unroll
    for (int p = 0; p < 2; ++p)
#pragma unroll
      for (int g = 0; g < 3; ++g)
        acc[p][g] = (f32x4){0.f, 0.f, 0.f, 0.f};

    const __fp16* hbuf = hA[i & 1];
#pragma unroll
    for (int kk = 0; kk < 8; ++kk) {
      f16x8 a = *(const f16x8*)&hbuf[kk * 32 + quad * 8];  // uniform per quad
#pragma unroll
      for (int p = 0; p < 2; ++p)
#pragma unroll
        for (int g = 0; g < 3; ++g)
          acc[p][g] = __builtin_amdgcn_mfma_f32_16x16x32_f16(
              a, Bf[p][g][kk], acc[p][g], 0, 0, 0);
    }

    // epilogue: all C rows identical -> use reg 0; quad-0 lanes write
    __fp16* hnext = hA[(i + 1) & 1];
#pragma unroll
    for (int p = 0; p < 2; ++p) {
      int j = jw + p * 16 + col;
      float rr = rcp_f(1.f + exp2_f(-LOG2E * ((float)gcur[p][0] + acc[p][0][0])));
      float zz = rcp_f(1.f + exp2_f(-LOG2E * ((float)gcur[p][1] + acc[p][1][0])));
      float na = fmaf(rr, acc[p][2][0] + bn[p], (float)gcur[p][2]);
      float nn = fmaf(-2.f, rcp_f(1.f + exp2_f(C2 * na)), 1.f);  // tanh
      float h = fmaf(zz, hold[p] - nn, nn);
      hold[p] = h;
      if (quad == 0) {
        out[((size_t)i * 32 + b) * 256 + j] = h;
        hnext[j] = (__fp16)h;
      }
    }
#pragma unroll
    for (int p = 0; p < 2; ++p)
#pragma unroll
      for (int g = 0; g < 3; ++g) gcur[p][g] = gnext[p][g];
    __syncthreads();
  }
}

// ---------------------------------------------------------------------------
extern "C" void kernel_launch(void* const* d_in, const int* in_sizes, int n_in,
                              void* d_out, int out_size, void* d_ws, size_t ws_size,
                              hipStream_t stream)
{
  const float* v   = (const float*)d_in[0];
  const float* h0  = (const float*)d_in[1];
  const float* Vv  = (const float*)d_in[2];
  const float* Wp  = (const float*)d_in[3];
  const float* Wp_ = (const float*)d_in[4];
  const float* Wih = (const float*)d_in[5];
  const float* Whh = (const float*)d_in[6];
  const float* bih = (const float*)d_in[7];
  const float* bhh = (const float*)d_in[8];
  float* out = (float*)d_out;
  float* ws  = (float*)d_ws;

  float* Eq = ws;
  float* Ev = ws + 4194304;
  float* S  = ws + 8388608;
  float* C  = ws;                          // reuse Eq (dead after score_k)
  __fp16* Gi2 = (__fp16*)(ws + 4194304);   // reuse Ev+S (dead after ctx_k)

  gemm_nt<<<dim3(4, 256), 256, 0, stream>>>(v, Wp,  nullptr, Eq, 256, 1);
  gemm_nt<<<dim3(4, 256), 256, 0, stream>>>(v, Wp_, nullptr, Ev, 256, 1);
  score_k<<<dim3(16, 8, 32), 256, 0, stream>>>(Eq, Ev, Vv, S);
  softmax_k<<<16384, 64, 0, stream>>>(S);
  ctx_k<<<dim3(4, 8, 32), 256, 0, stream>>>(S, v, C);
  gemm_gi<<<dim3(12, 256), 256, 0, stream>>>(C, Wih, bih, bhh, Gi2);
  gru_k<<<32, 512, 0, stream>>>(Gi2, Whh, bhh, h0, out);
}

// Round 9
// 940.316 us; speedup vs baseline: 2.8281x; 1.1250x over previous
//
#include <hip/hip_runtime.h>
#include <stdint.h>

// L=512, B=32, D=H=256
// Workspace layout (floats):
//   Eq  [16384*256] @ 0         (exp2(C2*xq))
//   Ev  [16384*256] @ 4194304   (exp2(C2*xv))
//   S   [32*512*512] @ 8388608  (scores, then softmax in place)
//   C   [16384*256] @ 0         (context, reuses Eq region - dead after score_k)
//   Gi2 [f16, 16384*768] @ float-offset 4194304, layout [i*32+b][g*256+j]

#define C2    2.8853900817779268f   // 2*log2(e)
#define LOG2E 1.4426950408889634f

typedef __fp16 f16x4_t __attribute__((ext_vector_type(4)));
typedef __fp16 f16x8 __attribute__((ext_vector_type(8)));
typedef float f32x4 __attribute__((ext_vector_type(4)));

static __device__ __forceinline__ float rcp_f(float x)  { return __builtin_amdgcn_rcpf(x); }
static __device__ __forceinline__ float exp2_f(float x) { return __builtin_amdgcn_exp2f(x); }
static __device__ __forceinline__ f16x8 cvt8(float4 a, float4 b) {
  f16x8 f;
  f[0] = (__fp16)a.x; f[1] = (__fp16)a.y; f[2] = (__fp16)a.z; f[3] = (__fp16)a.w;
  f[4] = (__fp16)b.x; f[5] = (__fp16)b.y; f[6] = (__fp16)b.z; f[7] = (__fp16)b.w;
  return f;
}

// Fragment conventions (verified end-to-end in gru R6-R8, absmax 0.0078):
//   A-frag: lane(col=lane&15, quad=lane>>4) holds A[m=col][k=quad*8+jj]
//   B-frag: lane holds B[k=quad*8+jj][n=col]
//   C/D:    row(m)=quad*4+reg, col(n)=lane&15

// ---------------------------------------------------------------------------
// Fused projections: Eq = exp2(C2 * v@Wp^T), Ev = exp2(C2 * v@Wp_^T).
// M=16384, N=256, K=256. grid (4 n-tiles, 256 m-tiles), block 256 (4 waves).
// Stages v tile once, both weight tiles; MFMA f16, fp32 accumulate.
// ---------------------------------------------------------------------------
__global__ __launch_bounds__(256) void proj_k(
    const float* __restrict__ v, const float* __restrict__ Wp,
    const float* __restrict__ Wp_, float* __restrict__ Eq,
    float* __restrict__ Ev)
{
  __shared__ __align__(16) __fp16 As[64][40];
  __shared__ __align__(16) __fp16 Wqs[64][40];
  __shared__ __align__(16) __fp16 Wvs[64][40];
  const int t = threadIdx.x, wave = t >> 6, lane = t & 63;
  const int quad = lane >> 4, col = lane & 15;
  const int n0 = blockIdx.x * 64, m0 = blockIdx.y * 64;
  const int srow = t >> 2, skq = t & 3;

  f32x4 accq[4], accv[4];
#pragma unroll
  for (int nt = 0; nt < 4; ++nt) {
    accq[nt] = (f32x4){0.f, 0.f, 0.f, 0.f};
    accv[nt] = (f32x4){0.f, 0.f, 0.f, 0.f};
  }

  for (int kc = 0; kc < 8; ++kc) {
    const int k0 = kc * 32;
    {
      const float4* ap = (const float4*)&v[(size_t)(m0 + srow) * 256 + k0 + skq * 8];
      *(f16x8*)&As[srow][skq * 8] = cvt8(ap[0], ap[1]);
      const float4* qp = (const float4*)&Wp[(size_t)(n0 + srow) * 256 + k0 + skq * 8];
      *(f16x8*)&Wqs[srow][skq * 8] = cvt8(qp[0], qp[1]);
      const float4* vp = (const float4*)&Wp_[(size_t)(n0 + srow) * 256 + k0 + skq * 8];
      *(f16x8*)&Wvs[srow][skq * 8] = cvt8(vp[0], vp[1]);
    }
    __syncthreads();
    f16x8 a = *(const f16x8*)&As[wave * 16 + col][quad * 8];
#pragma unroll
    for (int nt = 0; nt < 4; ++nt) {
      f16x8 bq = *(const f16x8*)&Wqs[nt * 16 + col][quad * 8];
      f16x8 bv = *(const f16x8*)&Wvs[nt * 16 + col][quad * 8];
      accq[nt] = __builtin_amdgcn_mfma_f32_16x16x32_f16(a, bq, accq[nt], 0, 0, 0);
      accv[nt] = __builtin_amdgcn_mfma_f32_16x16x32_f16(a, bv, accv[nt], 0, 0, 0);
    }
    __syncthreads();
  }

#pragma unroll
  for (int nt = 0; nt < 4; ++nt)
#pragma unroll
    for (int r = 0; r < 4; ++r) {
      size_t m = m0 + wave * 16 + quad * 4 + r;
      size_t n = n0 + nt * 16 + col;
      Eq[m * 256 + n] = exp2_f(C2 * accq[nt][r]);
      Ev[m * 256 + n] = exp2_f(C2 * accv[nt][r]);
    }
}

// ---------------------------------------------------------------------------
// Gi2 = f16( C @ Wih^T + bih (+bhh for gates r,z) ). M=16384, N=768, K=256.
// grid (12, 256), block 256.
// ---------------------------------------------------------------------------
__global__ __launch_bounds__(256) void gi_k(
    const float* __restrict__ A, const float* __restrict__ W,
    const float* __restrict__ bih, const float* __restrict__ bhh,
    __fp16* __restrict__ G)
{
  __shared__ __align__(16) __fp16 As[64][40];
  __shared__ __align__(16) __fp16 Ws[64][40];
  const int t = threadIdx.x, wave = t >> 6, lane = t & 63;
  const int quad = lane >> 4, col = lane & 15;
  const int n0 = blockIdx.x * 64, m0 = blockIdx.y * 64;
  const int srow = t >> 2, skq = t & 3;

  f32x4 acc[4];
#pragma unroll
  for (int nt = 0; nt < 4; ++nt) acc[nt] = (f32x4){0.f, 0.f, 0.f, 0.f};

  for (int kc = 0; kc < 8; ++kc) {
    const int k0 = kc * 32;
    {
      const float4* ap = (const float4*)&A[(size_t)(m0 + srow) * 256 + k0 + skq * 8];
      *(f16x8*)&As[srow][skq * 8] = cvt8(ap[0], ap[1]);
      const float4* wp = (const float4*)&W[(size_t)(n0 + srow) * 256 + k0 + skq * 8];
      *(f16x8*)&Ws[srow][skq * 8] = cvt8(wp[0], wp[1]);
    }
    __syncthreads();
    f16x8 a = *(const f16x8*)&As[wave * 16 + col][quad * 8];
#pragma unroll
    for (int nt = 0; nt < 4; ++nt) {
      f16x8 b = *(const f16x8*)&Ws[nt * 16 + col][quad * 8];
      acc[nt] = __builtin_amdgcn_mfma_f32_16x16x32_f16(a, b, acc[nt], 0, 0, 0);
    }
    __syncthreads();
  }

#pragma unroll
  for (int nt = 0; nt < 4; ++nt) {
    int n = n0 + nt * 16 + col;
    float bias = bih[n] + (n < 512 ? bhh[n] : 0.f);
#pragma unroll
    for (int r = 0; r < 4; ++r) {
      size_t m = m0 + wave * 16 + quad * 4 + r;
      G[m * 768 + n] = (__fp16)(acc[nt][r] + bias);
    }
  }
}

// ---------------------------------------------------------------------------
// Context via MFMA: C[i][b][d] = sum_l Aw[b][i][l] * v[l][b][d].
// grid (4 d-tiles, 8 i-tiles, 32 b), block 256. K=512 in 16 chunks of 32.
// v staged TRANSPOSED into Vs[d][l] so B-frags are contiguous b128 reads.
// ---------------------------------------------------------------------------
__global__ __launch_bounds__(256) void ctxm_k(
    const float* __restrict__ Aw, const float* __restrict__ v,
    float* __restrict__ C)
{
  __shared__ __align__(16) __fp16 As[64][40];
  __shared__ __align__(16) __fp16 Vs[64][40];
  const int t = threadIdx.x, wave = t >> 6, lane = t & 63;
  const int quad = lane >> 4, col = lane & 15;
  const int d0 = blockIdx.x * 64, i0 = blockIdx.y * 64, b = blockIdx.z;
  const int srow = t >> 2, skq = t & 3;     // A staging: 64 rows x 4 kq
  const int vl = t >> 3, vdq = t & 7;       // V staging: 32 l x 8 dq

  f32x4 acc[4];
#pragma unroll
  for (int nt = 0; nt < 4; ++nt) acc[nt] = (f32x4){0.f, 0.f, 0.f, 0.f};

  for (int kc = 0; kc < 16; ++kc) {
    const int l0 = kc * 32;
    {
      const float4* ap =
          (const float4*)&Aw[((size_t)b * 512 + i0 + srow) * 512 + l0 + skq * 8];
      *(f16x8*)&As[srow][skq * 8] = cvt8(ap[0], ap[1]);
      const float4* vp =
          (const float4*)&v[((size_t)(l0 + vl) * 32 + b) * 256 + d0 + vdq * 8];
      float4 v0 = vp[0], v1 = vp[1];
      float vv[8] = {v0.x, v0.y, v0.z, v0.w, v1.x, v1.y, v1.z, v1.w};
#pragma unroll
      for (int e = 0; e < 8; ++e) Vs[vdq * 8 + e][vl] = (__fp16)vv[e];
    }
    __syncthreads();
    f16x8 a = *(const f16x8*)&As[wave * 16 + col][quad * 8];
#pragma unroll
    for (int nt = 0; nt < 4; ++nt) {
      f16x8 bb = *(const f16x8*)&Vs[nt * 16 + col][quad * 8];
      acc[nt] = __builtin_amdgcn_mfma_f32_16x16x32_f16(a, bb, acc[nt], 0, 0, 0);
    }
    __syncthreads();
  }

#pragma unroll
  for (int nt = 0; nt < 4; ++nt)
#pragma unroll
    for (int r = 0; r < 4; ++r) {
      size_t i = i0 + wave * 16 + quad * 4 + r;
      size_t d = d0 + nt * 16 + col;
      C[(i * 32 + b) * 256 + d] = acc[nt][r];
    }
}

// ---------------------------------------------------------------------------
// S[b][i][l] = -2 * sum_h Vvec[b][h] * rcp(1 + Eq[i][b][h]*Ev[l][b][h])
// (transcendental-rate-bound; ~at floor)
// ---------------------------------------------------------------------------
__global__ __launch_bounds__(256) void score_k(
    const float* __restrict__ Eq, const float* __restrict__ Ev,
    const float* __restrict__ Vvec, float* __restrict__ S)
{
  __shared__ __align__(16) float Eqs[64][68];
  __shared__ __align__(16) float Evs[32][68];
  __shared__ __align__(16) float Vs[256];
  const int t = threadIdx.x;
  const int tx = t & 15, ty = t >> 4;
  const int l0 = blockIdx.x * 32;
  const int i0 = blockIdx.y * 64;
  const int b  = blockIdx.z;

  Vs[t] = -2.0f * Vvec[b * 256 + t];
  float acc[4][2] = {};

  for (int st = 0; st < 4; ++st) {
    const int h0 = st * 64;
#pragma unroll
    for (int s = 0; s < 4; ++s) {
      int f = t + s * 256;
      int row = f >> 4, cq = f & 15;
      *(float4*)&Eqs[row][cq * 4] =
          *(const float4*)&Eq[((size_t)(i0 + row) * 32 + b) * 256 + h0 + cq * 4];
    }
#pragma unroll
    for (int s = 0; s < 2; ++s) {
      int f = t + s * 256;
      int row = f >> 4, cq = f & 15;
      *(float4*)&Evs[row][cq * 4] =
          *(const float4*)&Ev[((size_t)(l0 + row) * 32 + b) * 256 + h0 + cq * 4];
    }
    __syncthreads();
#pragma unroll 4
    for (int k4 = 0; k4 < 16; ++k4) {
      float4 vh = *(const float4*)&Vs[h0 + k4 * 4];
      float4 e0 = *(const float4*)&Evs[tx][k4 * 4];
      float4 e1 = *(const float4*)&Evs[tx + 16][k4 * 4];
#pragma unroll
      for (int r = 0; r < 4; ++r) {
        float4 eq = *(const float4*)&Eqs[ty * 4 + r][k4 * 4];
        acc[r][0] += vh.x * rcp_f(fmaf(eq.x, e0.x, 1.0f));
        acc[r][0] += vh.y * rcp_f(fmaf(eq.y, e0.y, 1.0f));
        acc[r][0] += vh.z * rcp_f(fmaf(eq.z, e0.z, 1.0f));
        acc[r][0] += vh.w * rcp_f(fmaf(eq.w, e0.w, 1.0f));
        acc[r][1] += vh.x * rcp_f(fmaf(eq.x, e1.x, 1.0f));
        acc[r][1] += vh.y * rcp_f(fmaf(eq.y, e1.y, 1.0f));
        acc[r][1] += vh.z * rcp_f(fmaf(eq.z, e1.z, 1.0f));
        acc[r][1] += vh.w * rcp_f(fmaf(eq.w, e1.w, 1.0f));
      }
    }
    __syncthreads();
  }

#pragma unroll
  for (int r = 0; r < 4; ++r) {
    float* ps = &S[((size_t)b * 512 + i0 + ty * 4 + r) * 512 + l0];
    ps[tx]      = acc[r][0];
    ps[tx + 16] = acc[r][1];
  }
}

// ---------------------------------------------------------------------------
// In-place softmax over rows of 512. 4 rows/block (one wave each), float4.
// grid 4096, block 256.
// ---------------------------------------------------------------------------
__global__ __launch_bounds__(256) void softmax_k(float* __restrict__ S)
{
  const int wave = threadIdx.x >> 6, lane = threadIdx.x & 63;
  float* row = &S[((size_t)blockIdx.x * 4 + wave) * 512];
  float4 x0 = *(float4*)&row[lane * 4];
  float4 x1 = *(float4*)&row[256 + lane * 4];
  float m = fmaxf(fmaxf(fmaxf(x0.x, x0.y), fmaxf(x0.z, x0.w)),
                  fmaxf(fmaxf(x1.x, x1.y), fmaxf(x1.z, x1.w)));
#pragma unroll
  for (int o = 32; o; o >>= 1) m = fmaxf(m, __shfl_xor(m, o, 64));
  x0.x = exp2_f(LOG2E * (x0.x - m)); x0.y = exp2_f(LOG2E * (x0.y - m));
  x0.z = exp2_f(LOG2E * (x0.z - m)); x0.w = exp2_f(LOG2E * (x0.w - m));
  x1.x = exp2_f(LOG2E * (x1.x - m)); x1.y = exp2_f(LOG2E * (x1.y - m));
  x1.z = exp2_f(LOG2E * (x1.z - m)); x1.w = exp2_f(LOG2E * (x1.w - m));
  float sum = x0.x + x0.y + x0.z + x0.w + x1.x + x1.y + x1.z + x1.w;
#pragma unroll
  for (int o = 32; o; o >>= 1) sum += __shfl_xor(sum, o, 64);
  float inv = rcp_f(sum);
  x0.x *= inv; x0.y *= inv; x0.z *= inv; x0.w *= inv;
  x1.x *= inv; x1.y *= inv; x1.z *= inv; x1.w *= inv;
  *(float4*)&row[lane * 4] = x0;
  *(float4*)&row[256 + lane * 4] = x1;
}

// ---------------------------------------------------------------------------
// MFMA GRU, one batch per block (32 blocks x 512 threads). Unchanged from R8
// (554 us; near the broadcast-M MFMA-pipe floor of ~1.9k cyc/step/CU).
// ---------------------------------------------------------------------------
__global__ __launch_bounds__(512, 1) void gru_k(
    const __fp16* __restrict__ Gi2, const float* __restrict__ Whh,
    const float* __restrict__ bhh, const float* __restrict__ h0,
    float* __restrict__ out)
{
  __shared__ __align__(16) __fp16 hA[2][256];
  const int t = threadIdx.x, wave = t >> 6, lane = t & 63;
  const int quad = lane >> 4, col = lane & 15;
  const int b = blockIdx.x;
  const int jw = wave * 32;

  f16x8 Bf[2][3][8];
#pragma unroll
  for (int p = 0; p < 2; ++p)
#pragma unroll
    for (int g = 0; g < 3; ++g) {
      const float* wrow = &Whh[(size_t)(g * 256 + jw + p * 16 + col) * 256];
#pragma unroll
      for (int kk = 0; kk < 8; ++kk) {
        const float4* wp = (const float4*)&wrow[kk * 32 + quad * 8];
        Bf[p][g][kk] = cvt8(wp[0], wp[1]);
      }
    }

  float hold[2];
  float bn[2];
#pragma unroll
  for (int p = 0; p < 2; ++p) {
    int j = jw + p * 16 + col;
    bn[p] = bhh[512 + j];
    float h = h0[(size_t)b * 256 + j];
    hold[p] = h;
    if (quad == 0) hA[0][j] = (__fp16)h;
  }
  __syncthreads();

  __fp16 gcur[2][3];
#pragma unroll
  for (int p = 0; p < 2; ++p)
#pragma unroll
    for (int g = 0; g < 3; ++g)
      gcur[p][g] = Gi2[(size_t)b * 768 + g * 256 + jw + p * 16 + col];

  for (int i = 0; i < 512; ++i) {
    __fp16 gnext[2][3];
    {
      int ip = (i + 1 < 512) ? (i + 1) : 511;
#pragma unroll
      for (int p = 0; p < 2; ++p)
#pragma unroll
        for (int g = 0; g < 3; ++g)
          gnext[p][g] =
              Gi2[(size_t)(ip * 32 + b) * 768 + g * 256 + jw + p * 16 + col];
    }

    f32x4 acc[2][3];
#pragma unroll
    for (int p = 0; p < 2; ++p)
#pragma unroll
      for (int g = 0; g < 3; ++g)
        acc[p][g] = (f32x4){0.f, 0.f, 0.f, 0.f};

    const __fp16* hbuf = hA[i & 1];
#pragma unroll
    for (int kk = 0; kk < 8; ++kk) {
      f16x8 a = *(const f16x8*)&hbuf[kk * 32 + quad * 8];
#pragma unroll
      for (int p = 0; p < 2; ++p)
#pragma unroll
        for (int g = 0; g < 3; ++g)
          acc[p][g] = __builtin_amdgcn_mfma_f32_16x16x32_f16(
              a, Bf[p][g][kk], acc[p][g], 0, 0, 0);
    }

    __fp16* hnext = hA[(i + 1) & 1];
#pragma unroll
    for (int p = 0; p < 2; ++p) {
      int j = jw + p * 16 + col;
      float rr = rcp_f(1.f + exp2_f(-LOG2E * ((float)gcur[p][0] + acc[p][0][0])));
      float zz = rcp_f(1.f + exp2_f(-LOG2E * ((float)gcur[p][1] + acc[p][1][0])));
      float na = fmaf(rr, acc[p][2][0] + bn[p], (float)gcur[p][2]);
      float nn = fmaf(-2.f, rcp_f(1.f + exp2_f(C2 * na)), 1.f);
      float h = fmaf(zz, hold[p] - nn, nn);
      hold[p] = h;
      if (quad == 0) {
        out[((size_t)i * 32 + b) * 256 + j] = h;
        hnext[j] = (__fp16)h;
      }
    }
#pragma unroll
    for (int p = 0; p < 2; ++p)
#pragma unroll
      for (int g = 0; g < 3; ++g) gcur[p][g] = gnext[p][g];
    __syncthreads();
  }
}

// ---------------------------------------------------------------------------
extern "C" void kernel_launch(void* const* d_in, const int* in_sizes, int n_in,
                              void* d_out, int out_size, void* d_ws, size_t ws_size,
                              hipStream_t stream)
{
  const float* v   = (const float*)d_in[0];
  const float* h0  = (const float*)d_in[1];
  const float* Vv  = (const float*)d_in[2];
  const float* Wp  = (const float*)d_in[3];
  const float* Wp_ = (const float*)d_in[4];
  const float* Wih = (const float*)d_in[5];
  const float* Whh = (const float*)d_in[6];
  const float* bih = (const float*)d_in[7];
  const float* bhh = (const float*)d_in[8];
  float* out = (float*)d_out;
  float* ws  = (float*)d_ws;

  float* Eq = ws;
  float* Ev = ws + 4194304;
  float* S  = ws + 8388608;
  float* C  = ws;                          // reuse Eq (dead after score_k)
  __fp16* Gi2 = (__fp16*)(ws + 4194304);   // reuse Ev+S (dead after ctxm_k)

  proj_k<<<dim3(4, 256), 256, 0, stream>>>(v, Wp, Wp_, Eq, Ev);
  score_k<<<dim3(16, 8, 32), 256, 0, stream>>>(Eq, Ev, Vv, S);
  softmax_k<<<4096, 256, 0, stream>>>(S);
  ctxm_k<<<dim3(4, 8, 32), 256, 0, stream>>>(S, v, C);
  gi_k<<<dim3(12, 256), 256, 0, stream>>>(C, Wih, bih, bhh, Gi2);
  gru_k<<<32, 512, 0, stream>>>(Gi2, Whh, bhh, h0, out);
}

// Round 11
// 921.197 us; speedup vs baseline: 2.8868x; 1.0208x over previous
//
#include <hip/hip_runtime.h>
#include <stdint.h>

// L=512, B=32, D=H=256
// Workspace (floats):
//   Eq [f16 16384*256] @ 0, Ev [f16] @ 4194304, S @ 8388608,
//   C @ 0 (reuse), Gi2 [f16] @ 4194304 (reuse)

#define C2    2.8853900817779268f   // 2*log2(e)
#define LOG2E 1.4426950408889634f

typedef __fp16 f16x2 __attribute__((ext_vector_type(2)));
typedef __fp16 f16x4_t __attribute__((ext_vector_type(4)));
typedef __fp16 f16x8 __attribute__((ext_vector_type(8)));
typedef float f32x4 __attribute__((ext_vector_type(4)));

static __device__ __forceinline__ float rcp_f(float x)  { return __builtin_amdgcn_rcpf(x); }
static __device__ __forceinline__ float exp2_f(float x) { return __builtin_amdgcn_exp2f(x); }
#if __has_builtin(__builtin_amdgcn_rcph)
static __device__ __forceinline__ __fp16 rcph(__fp16 x) {
  return (__fp16)__builtin_amdgcn_rcph((_Float16)x);
}
#else
static __device__ __forceinline__ __fp16 rcph(__fp16 x) {
  return (__fp16)__builtin_amdgcn_rcpf((float)x);
}
#endif
static __device__ __forceinline__ float dot2f(f16x2 a, f16x2 b, float c) {
  return __builtin_amdgcn_fdot2(a, b, c, false);
}
static __device__ __forceinline__ f16x8 cvt8(float4 a, float4 b) {
  f16x8 f;
  f[0] = (__fp16)a.x; f[1] = (__fp16)a.y; f[2] = (__fp16)a.z; f[3] = (__fp16)a.w;
  f[4] = (__fp16)b.x; f[5] = (__fp16)b.y; f[6] = (__fp16)b.z; f[7] = (__fp16)b.w;
  return f;
}

// Fragment conventions (verified end-to-end):
//   A-frag: lane(col=lane&15, quad=lane>>4) holds A[m=col][k=quad*8+jj]
//   B-frag: lane holds B[k=quad*8+jj][n=col]
//   C/D:    row(m)=quad*4+reg, col(n)=lane&15

// ---------------------------------------------------------------------------
// Fused projections -> f16 with exponent clamp to f16-normal range:
// Eq = exp2(clamp(C2*v@Wp^T, -14, 15.5)) etc.  No inf, no 0 -> no NaN in
// score's pk_fma (inf can only arise from the product, which rcp's to the
// correct saturation limit).
// ---------------------------------------------------------------------------
__global__ __launch_bounds__(256) void proj_k(
    const float* __restrict__ v, const float* __restrict__ Wp,
    const float* __restrict__ Wp_, __fp16* __restrict__ Eq,
    __fp16* __restrict__ Ev)
{
  __shared__ __align__(16) __fp16 As[64][40];
  __shared__ __align__(16) __fp16 Wqs[64][40];
  __shared__ __align__(16) __fp16 Wvs[64][40];
  const int t = threadIdx.x, wave = t >> 6, lane = t & 63;
  const int quad = lane >> 4, col = lane & 15;
  const int n0 = blockIdx.x * 64, m0 = blockIdx.y * 64;
  const int srow = t >> 2, skq = t & 3;

  f32x4 accq[4], accv[4];
#pragma unroll
  for (int nt = 0; nt < 4; ++nt) {
    accq[nt] = (f32x4){0.f, 0.f, 0.f, 0.f};
    accv[nt] = (f32x4){0.f, 0.f, 0.f, 0.f};
  }

  for (int kc = 0; kc < 8; ++kc) {
    const int k0 = kc * 32;
    {
      const float4* ap = (const float4*)&v[(size_t)(m0 + srow) * 256 + k0 + skq * 8];
      *(f16x8*)&As[srow][skq * 8] = cvt8(ap[0], ap[1]);
      const float4* qp = (const float4*)&Wp[(size_t)(n0 + srow) * 256 + k0 + skq * 8];
      *(f16x8*)&Wqs[srow][skq * 8] = cvt8(qp[0], qp[1]);
      const float4* vp = (const float4*)&Wp_[(size_t)(n0 + srow) * 256 + k0 + skq * 8];
      *(f16x8*)&Wvs[srow][skq * 8] = cvt8(vp[0], vp[1]);
    }
    __syncthreads();
    f16x8 a = *(const f16x8*)&As[wave * 16 + col][quad * 8];
#pragma unroll
    for (int nt = 0; nt < 4; ++nt) {
      f16x8 bq = *(const f16x8*)&Wqs[nt * 16 + col][quad * 8];
      f16x8 bv = *(const f16x8*)&Wvs[nt * 16 + col][quad * 8];
      accq[nt] = __builtin_amdgcn_mfma_f32_16x16x32_f16(a, bq, accq[nt], 0, 0, 0);
      accv[nt] = __builtin_amdgcn_mfma_f32_16x16x32_f16(a, bv, accv[nt], 0, 0, 0);
    }
    __syncthreads();
  }

#pragma unroll
  for (int nt = 0; nt < 4; ++nt)
#pragma unroll
    for (int r = 0; r < 4; ++r) {
      size_t m = m0 + wave * 16 + quad * 4 + r;
      size_t n = n0 + nt * 16 + col;
      float eq = C2 * accq[nt][r], ev = C2 * accv[nt][r];
      eq = fminf(fmaxf(eq, -14.f), 15.5f);
      ev = fminf(fmaxf(ev, -14.f), 15.5f);
      Eq[m * 256 + n] = (__fp16)exp2_f(eq);
      Ev[m * 256 + n] = (__fp16)exp2_f(ev);
    }
}

// ---------------------------------------------------------------------------
// Packed-f16 score: S[b][i][l] = -2 * sum_h V[b][h] * rcp(1 + Eq*Ev).
// Per 2 h: v_pk_fma_f16 + 2x rcp_f16 (trans pipe) + v_dot2_f32_f16 (fp32 acc).
// grid (16 l-tiles, 8 i-tiles, 32 b), block 256 (tx=16 l, ty=16 i).
// ---------------------------------------------------------------------------
__global__ __launch_bounds__(256) void score_k(
    const __fp16* __restrict__ Eq, const __fp16* __restrict__ Ev,
    const float* __restrict__ Vvec, float* __restrict__ S)
{
  __shared__ __align__(16) __fp16 Eqs[64][72];
  __shared__ __align__(16) __fp16 Evs[32][72];
  __shared__ __align__(16) __fp16 Vs[256];
  const int t = threadIdx.x;
  const int tx = t & 15, ty = t >> 4;
  const int l0 = blockIdx.x * 32;
  const int i0 = blockIdx.y * 64;
  const int b  = blockIdx.z;

  Vs[t] = (__fp16)(-2.0f * Vvec[b * 256 + t]);
  float acc[4][2] = {};
  const f16x2 one2 = {(__fp16)1.f, (__fp16)1.f};

  for (int st = 0; st < 4; ++st) {
    const int h0 = st * 64;
    // Eq: 64 rows x 8 chunks of 8 halfs = 512 chunks, 2 per thread
#pragma unroll
    for (int s = 0; s < 2; ++s) {
      int f = t + s * 256;
      int row = f >> 3, cq = f & 7;
      *(f16x8*)&Eqs[row][cq * 8] =
          *(const f16x8*)&Eq[((size_t)(i0 + row) * 32 + b) * 256 + h0 + cq * 8];
    }
    // Ev: 32 rows x 8 chunks = 256 chunks, 1 per thread
    {
      int row = t >> 3, cq = t & 7;
      *(f16x8*)&Evs[row][cq * 8] =
          *(const f16x8*)&Ev[((size_t)(l0 + row) * 32 + b) * 256 + h0 + cq * 8];
    }
    __syncthreads();

#pragma unroll
    for (int k8 = 0; k8 < 8; ++k8) {
      f16x8 vh8 = *(const f16x8*)&Vs[h0 + k8 * 8];
      f16x8 ev80 = *(const f16x8*)&Evs[tx][k8 * 8];
      f16x8 ev81 = *(const f16x8*)&Evs[tx + 16][k8 * 8];
      f16x8 eq8[4];
#pragma unroll
      for (int r = 0; r < 4; ++r)
        eq8[r] = *(const f16x8*)&Eqs[ty * 4 + r][k8 * 8];
#pragma unroll
      for (int q = 0; q < 4; ++q) {
        f16x2 vh2 = {vh8[q * 2], vh8[q * 2 + 1]};
        f16x2 e0  = {ev80[q * 2], ev80[q * 2 + 1]};
        f16x2 e1  = {ev81[q * 2], ev81[q * 2 + 1]};
#pragma unroll
        for (int r = 0; r < 4; ++r) {
          f16x2 eq2 = {eq8[r][q * 2], eq8[r][q * 2 + 1]};
          f16x2 d0 = eq2 * e0 + one2;   // v_pk_fma_f16
          f16x2 d1 = eq2 * e1 + one2;
          f16x2 r0 = {rcph(d0[0]), rcph(d0[1])};
          f16x2 r1 = {rcph(d1[0]), rcph(d1[1])};
          acc[r][0] = dot2f(vh2, r0, acc[r][0]);
          acc[r][1] = dot2f(vh2, r1, acc[r][1]);
        }
      }
    }
    __syncthreads();
  }

#pragma unroll
  for (int r = 0; r < 4; ++r) {
    float* ps = &S[((size_t)b * 512 + i0 + ty * 4 + r) * 512 + l0];
    ps[tx]      = acc[r][0];
    ps[tx + 16] = acc[r][1];
  }
}

// ---------------------------------------------------------------------------
// In-place softmax over rows of 512. 4 rows/block (one wave each), float4.
// ---------------------------------------------------------------------------
__global__ __launch_bounds__(256) void softmax_k(float* __restrict__ S)
{
  const int wave = threadIdx.x >> 6, lane = threadIdx.x & 63;
  float* row = &S[((size_t)blockIdx.x * 4 + wave) * 512];
  float4 x0 = *(float4*)&row[lane * 4];
  float4 x1 = *(float4*)&row[256 + lane * 4];
  float m = fmaxf(fmaxf(fmaxf(x0.x, x0.y), fmaxf(x0.z, x0.w)),
                  fmaxf(fmaxf(x1.x, x1.y), fmaxf(x1.z, x1.w)));
#pragma unroll
  for (int o = 32; o; o >>= 1) m = fmaxf(m, __shfl_xor(m, o, 64));
  x0.x = exp2_f(LOG2E * (x0.x - m)); x0.y = exp2_f(LOG2E * (x0.y - m));
  x0.z = exp2_f(LOG2E * (x0.z - m)); x0.w = exp2_f(LOG2E * (x0.w - m));
  x1.x = exp2_f(LOG2E * (x1.x - m)); x1.y = exp2_f(LOG2E * (x1.y - m));
  x1.z = exp2_f(LOG2E * (x1.z - m)); x1.w = exp2_f(LOG2E * (x1.w - m));
  float sum = x0.x + x0.y + x0.z + x0.w + x1.x + x1.y + x1.z + x1.w;
#pragma unroll
  for (int o = 32; o; o >>= 1) sum += __shfl_xor(sum, o, 64);
  float inv = rcp_f(sum);
  x0.x *= inv; x0.y *= inv; x0.z *= inv; x0.w *= inv;
  x1.x *= inv; x1.y *= inv; x1.z *= inv; x1.w *= inv;
  *(float4*)&row[lane * 4] = x0;
  *(float4*)&row[256 + lane * 4] = x1;
}

// ---------------------------------------------------------------------------
// Context via MFMA: C[i][b][d] = sum_l Aw[b][i][l] * v[l][b][d].
// ---------------------------------------------------------------------------
__global__ __launch_bounds__(256) void ctxm_k(
    const float* __restrict__ Aw, const float* __restrict__ v,
    float* __restrict__ C)
{
  __shared__ __align__(16) __fp16 As[64][40];
  __shared__ __align__(16) __fp16 Vs[64][40];
  const int t = threadIdx.x, wave = t >> 6, lane = t & 63;
  const int quad = lane >> 4, col = lane & 15;
  const int d0 = blockIdx.x * 64, i0 = blockIdx.y * 64, b = blockIdx.z;
  const int srow = t >> 2, skq = t & 3;
  const int vl = t >> 3, vdq = t & 7;

  f32x4 acc[4];
#pragma unroll
  for (int nt = 0; nt < 4; ++nt) acc[nt] = (f32x4){0.f, 0.f, 0.f, 0.f};

  for (int kc = 0; kc < 16; ++kc) {
    const int l0 = kc * 32;
    {
      const float4* ap =
          (const float4*)&Aw[((size_t)b * 512 + i0 + srow) * 512 + l0 + skq * 8];
      *(f16x8*)&As[srow][skq * 8] = cvt8(ap[0], ap[1]);
      const float4* vp =
          (const float4*)&v[((size_t)(l0 + vl) * 32 + b) * 256 + d0 + vdq * 8];
      float4 v0 = vp[0], v1 = vp[1];
      float vv[8] = {v0.x, v0.y, v0.z, v0.w, v1.x, v1.y, v1.z, v1.w};
#pragma unroll
      for (int e = 0; e < 8; ++e) Vs[vdq * 8 + e][vl] = (__fp16)vv[e];
    }
    __syncthreads();
    f16x8 a = *(const f16x8*)&As[wave * 16 + col][quad * 8];
#pragma unroll
    for (int nt = 0; nt < 4; ++nt) {
      f16x8 bb = *(const f16x8*)&Vs[nt * 16 + col][quad * 8];
      acc[nt] = __builtin_amdgcn_mfma_f32_16x16x32_f16(a, bb, acc[nt], 0, 0, 0);
    }
    __syncthreads();
  }

#pragma unroll
  for (int nt = 0; nt < 4; ++nt)
#pragma unroll
    for (int r = 0; r < 4; ++r) {
      size_t i = i0 + wave * 16 + quad * 4 + r;
      size_t d = d0 + nt * 16 + col;
      C[(i * 32 + b) * 256 + d] = acc[nt][r];
    }
}

// ---------------------------------------------------------------------------
// Gi2 = f16( C @ Wih^T + bih (+bhh for gates r,z) ). M=16384, N=768, K=256.
// ---------------------------------------------------------------------------
__global__ __launch_bounds__(256) void gi_k(
    const float* __restrict__ A, const float* __restrict__ W,
    const float* __restrict__ bih, const float* __restrict__ bhh,
    __fp16* __restrict__ G)
{
  __shared__ __align__(16) __fp16 As[64][40];
  __shared__ __align__(16) __fp16 Ws[64][40];
  const int t = threadIdx.x, wave = t >> 6, lane = t & 63;
  const int quad = lane >> 4, col = lane & 15;
  const int n0 = blockIdx.x * 64, m0 = blockIdx.y * 64;
  const int srow = t >> 2, skq = t & 3;

  f32x4 acc[4];
#pragma unroll
  for (int nt = 0; nt < 4; ++nt) acc[nt] = (f32x4){0.f, 0.f, 0.f, 0.f};

  for (int kc = 0; kc < 8; ++kc) {
    const int k0 = kc * 32;
    {
      const float4* ap = (const float4*)&A[(size_t)(m0 + srow) * 256 + k0 + skq * 8];
      *(f16x8*)&As[srow][skq * 8] = cvt8(ap[0], ap[1]);
      const float4* wp = (const float4*)&W[(size_t)(n0 + srow) * 256 + k0 + skq * 8];
      *(f16x8*)&Ws[srow][skq * 8] = cvt8(wp[0], wp[1]);
    }
    __syncthreads();
    f16x8 a = *(const f16x8*)&As[wave * 16 + col][quad * 8];
#pragma unroll
    for (int nt = 0; nt < 4; ++nt) {
      f16x8 b = *(const f16x8*)&Ws[nt * 16 + col][quad * 8];
      acc[nt] = __builtin_amdgcn_mfma_f32_16x16x32_f16(a, b, acc[nt], 0, 0, 0);
    }
    __syncthreads();
  }

#pragma unroll
  for (int nt = 0; nt < 4; ++nt) {
    int n = n0 + nt * 16 + col;
    float bias = bih[n] + (n < 512 ? bhh[n] : 0.f);
#pragma unroll
    for (int r = 0; r < 4; ++r) {
      size_t m = m0 + wave * 16 + quad * 4 + r;
      G[m * 768 + n] = (__fp16)(acc[nt][r] + bias);
    }
  }
}

// ---------------------------------------------------------------------------
// MFMA GRU, one batch per block (32 blocks x 512 threads). Unchanged from R8.
// ---------------------------------------------------------------------------
__global__ __launch_bounds__(512, 1) void gru_k(
    const __fp16* __restrict__ Gi2, const float* __restrict__ Whh,
    const float* __restrict__ bhh, const float* __restrict__ h0,
    float* __restrict__ out)
{
  __shared__ __align__(16) __fp16 hA[2][256];
  const int t = threadIdx.x, wave = t >> 6, lane = t & 63;
  const int quad = lane >> 4, col = lane & 15;
  const int b = blockIdx.x;
  const int jw = wave * 32;

  f16x8 Bf[2][3][8];
#pragma unroll
  for (int p = 0; p < 2; ++p)
#pragma unroll
    for (int g = 0; g < 3; ++g) {
      const float* wrow = &Whh[(size_t)(g * 256 + jw + p * 16 + col) * 256];
#pragma unroll
      for (int kk = 0; kk < 8; ++kk) {
        const float4* wp = (const float4*)&wrow[kk * 32 + quad * 8];
        Bf[p][g][kk] = cvt8(wp[0], wp[1]);
      }
    }

  float hold[2];
  float bn[2];
#pragma unroll
  for (int p = 0; p < 2; ++p) {
    int j = jw + p * 16 + col;
    bn[p] = bhh[512 + j];
    float h = h0[(size_t)b * 256 + j];
    hold[p] = h;
    if (quad == 0) hA[0][j] = (__fp16)h;
  }
  __syncthreads();

  __fp16 gcur[2][3];
#pragma unroll
  for (int p = 0; p < 2; ++p)
#pragma unroll
    for (int g = 0; g < 3; ++g)
      gcur[p][g] = Gi2[(size_t)b * 768 + g * 256 + jw + p * 16 + col];

  for (int i = 0; i < 512; ++i) {
    __fp16 gnext[2][3];
    {
      int ip = (i + 1 < 512) ? (i + 1) : 511;
#pragma unroll
      for (int p = 0; p < 2; ++p)
#pragma unroll
        for (int g = 0; g < 3; ++g)
          gnext[p][g] =
              Gi2[(size_t)(ip * 32 + b) * 768 + g * 256 + jw + p * 16 + col];
    }

    f32x4 acc[2][3];
#pragma unroll
    for (int p = 0; p < 2; ++p)
#pragma unroll
      for (int g = 0; g < 3; ++g)
        acc[p][g] = (f32x4){0.f, 0.f, 0.f, 0.f};

    const __fp16* hbuf = hA[i & 1];
#pragma unroll
    for (int kk = 0; kk < 8; ++kk) {
      f16x8 a = *(const f16x8*)&hbuf[kk * 32 + quad * 8];
#pragma unroll
      for (int p = 0; p < 2; ++p)
#pragma unroll
        for (int g = 0; g < 3; ++g)
          acc[p][g] = __builtin_amdgcn_mfma_f32_16x16x32_f16(
              a, Bf[p][g][kk], acc[p][g], 0, 0, 0);
    }

    __fp16* hnext = hA[(i + 1) & 1];
#pragma unroll
    for (int p = 0; p < 2; ++p) {
      int j = jw + p * 16 + col;
      float rr = rcp_f(1.f + exp2_f(-LOG2E * ((float)gcur[p][0] + acc[p][0][0])));
      float zz = rcp_f(1.f + exp2_f(-LOG2E * ((float)gcur[p][1] + acc[p][1][0])));
      float na = fmaf(rr, acc[p][2][0] + bn[p], (float)gcur[p][2]);
      float nn = fmaf(-2.f, rcp_f(1.f + exp2_f(C2 * na)), 1.f);
      float h = fmaf(zz, hold[p] - nn, nn);
      hold[p] = h;
      if (quad == 0) {
        out[((size_t)i * 32 + b) * 256 + j] = h;
        hnext[j] = (__fp16)h;
      }
    }
#pragma unroll
    for (int p = 0; p < 2; ++p)
#pragma unroll
      for (int g = 0; g < 3; ++g) gcur[p][g] = gnext[p][g];
    __syncthreads();
  }
}

// ---------------------------------------------------------------------------
extern "C" void kernel_launch(void* const* d_in, const int* in_sizes, int n_in,
                              void* d_out, int out_size, void* d_ws, size_t ws_size,
                              hipStream_t stream)
{
  const float* v   = (const float*)d_in[0];
  const float* h0  = (const float*)d_in[1];
  const float* Vv  = (const float*)d_in[2];
  const float* Wp  = (const float*)d_in[3];
  const float* Wp_ = (const float*)d_in[4];
  const float* Wih = (const float*)d_in[5];
  const float* Whh = (const float*)d_in[6];
  const float* bih = (const float*)d_in[7];
  const float* bhh = (const float*)d_in[8];
  float* out = (float*)d_out;
  float* ws  = (float*)d_ws;

  __fp16* Eq = (__fp16*)ws;
  __fp16* Ev = (__fp16*)(ws + 4194304);
  float*  S  = ws + 8388608;
  float*  C  = ws;                         // reuse Eq region
  __fp16* Gi2 = (__fp16*)(ws + 4194304);   // reuse Ev+S regions

  proj_k<<<dim3(4, 256), 256, 0, stream>>>(v, Wp, Wp_, Eq, Ev);
  score_k<<<dim3(16, 8, 32), 256, 0, stream>>>(Eq, Ev, Vv, S);
  softmax_k<<<4096, 256, 0, stream>>>(S);
  ctxm_k<<<dim3(4, 8, 32), 256, 0, stream>>>(S, v, C);
  gi_k<<<dim3(12, 256), 256, 0, stream>>>(C, Wih, bih, bhh, Gi2);
  gru_k<<<32, 512, 0, stream>>>(Gi2, Whh, bhh, h0, out);
}